// Round 1
// baseline (659.925 us; speedup 1.0000x reference)
//
#include <hip/hip_runtime.h>
#include <hip/hip_bf16.h>
#include <math.h>

// Problem constants: B=1, S=2048, DIM=1024, QH=16, KVH=4, DH=64
#define S_LEN 2048

// ---------------- generic f32 tiled GEMM: C[M,N] = A[M,K] @ B[K,N] ----------
// requires M%64==0, N%64==0, K%16==0
__global__ __launch_bounds__(256) void gemm_f32_k(
    const float* __restrict__ A, const float* __restrict__ B,
    float* __restrict__ C, int M, int N, int K) {
  __shared__ float As[64][17];   // [m][k], pad breaks bank conflicts
  __shared__ float Bs[16][64];   // [k][n]
  int tid = threadIdx.x;
  int tx = tid & 15, ty = tid >> 4;
  int n0 = blockIdx.x * 64, m0 = blockIdx.y * 64;
  float acc[4][4] = {{0.f}};
  for (int k0 = 0; k0 < K; k0 += 16) {
    {
      int kk = tid & 15, mm = tid >> 4;
#pragma unroll
      for (int p = 0; p < 4; ++p)
        As[mm + p * 16][kk] = A[(size_t)(m0 + mm + p * 16) * K + k0 + kk];
    }
    {
      int nn = tid & 63, kb = tid >> 6;
#pragma unroll
      for (int p = 0; p < 4; ++p)
        Bs[kb + p * 4][nn] = B[(size_t)(k0 + kb + p * 4) * N + n0 + nn];
    }
    __syncthreads();
#pragma unroll
    for (int kq = 0; kq < 16; ++kq) {
      float a[4], b[4];
#pragma unroll
      for (int i = 0; i < 4; ++i) a[i] = As[ty * 4 + i][kq];
#pragma unroll
      for (int j = 0; j < 4; ++j) b[j] = Bs[kq][tx * 4 + j];
#pragma unroll
      for (int i = 0; i < 4; ++i)
#pragma unroll
        for (int j = 0; j < 4; ++j) acc[i][j] += a[i] * b[j];
    }
    __syncthreads();
  }
#pragma unroll
  for (int i = 0; i < 4; ++i)
#pragma unroll
    for (int j = 0; j < 4; ++j)
      C[(size_t)(m0 + ty * 4 + i) * N + n0 + tx * 4 + j] = acc[i][j];
}

// ---------------- postprocess: g/m dots, v-mix, k RMS+scale+RoPE, q RoPE ----
__global__ __launch_bounds__(256) void postproc_k(
    const float* __restrict__ x, const int* __restrict__ positions,
    const float* __restrict__ Wg, const float* __restrict__ Wm,
    const float* __restrict__ bm, const float* __restrict__ ksc,
    float* __restrict__ q, float* __restrict__ k, float* __restrict__ v,
    const float* __restrict__ rv, float* __restrict__ g_out) {
  int s = blockIdx.x;
  int tid = threadIdx.x;
  int lane = tid & 63, w = tid >> 6;
  __shared__ float xs[1024];
  __shared__ float dots[20];
  {
    const float4* xg = (const float4*)(x + (size_t)s * 1024);
    ((float4*)xs)[tid] = xg[tid];
  }
  __syncthreads();
  // 20 dot products over the x row: j<16 -> Wg col j, j>=16 -> Wm col j-16
  for (int j = w; j < 20; j += 4) {
    const float* W;
    int ldw;
    if (j < 16) { W = Wg + j; ldw = 16; } else { W = Wm + (j - 16); ldw = 4; }
    float p = 0.f;
#pragma unroll
    for (int d0 = 0; d0 < 16; ++d0) {
      int d = d0 * 64 + lane;
      p += xs[d] * W[(size_t)d * ldw];
    }
#pragma unroll
    for (int off = 32; off > 0; off >>= 1) p += __shfl_xor(p, off);
    if (lane == 0) dots[j] = p;
  }
  __syncthreads();
  int pos = positions[s];
  const float LOG1E4_OVER_64 = 9.210340371976184f / 64.f;
  // v = v + sigmoid(m)*(rv - v) ; wave w = kv-head h, lane = d
  {
    int h = w, d = lane;
    float mixv = 1.f / (1.f + __expf(-(dots[16 + h] + bm[h])));
    size_t idx = (size_t)s * 256 + h * 64 + d;
    float vv = v[idx];
    v[idx] = vv + mixv * (rv[idx] - vv);
  }
  if (tid < 16) g_out[s * 16 + tid] = 1.f / (1.f + __expf(-dots[tid]));
  // k: RMSNorm over dh, * k_scale, then RoPE
  {
    int h = w, d = lane;
    size_t idx = (size_t)s * 256 + h * 64 + d;
    float kv = k[idx];
    float ss = kv * kv;
#pragma unroll
    for (int off = 32; off > 0; off >>= 1) ss += __shfl_xor(ss, off);
    float rms = sqrtf(ss * (1.f / 64.f) + 1e-8f);
    float kn = kv / rms * ksc[h * 64 + d];
    float fr = (float)pos * __expf(-(float)(d & ~1) * LOG1E4_OVER_64);
    float c = cosf(fr), sn = sinf(fr);
    float partner = __shfl_xor(kn, 1);
    k[idx] = (d & 1) ? fmaf(kn, c, partner * sn) : fmaf(kn, c, -partner * sn);
  }
  // q RoPE (1024 dims, 4 per thread; pair partner is lane^1)
#pragma unroll
  for (int r = 0; r < 4; ++r) {
    int e = r * 256 + tid;
    int d = e & 63;
    size_t idx = (size_t)s * 1024 + e;
    float qv = q[idx];
    float fr = (float)pos * __expf(-(float)(d & ~1) * LOG1E4_OVER_64);
    float c = cosf(fr), sn = sinf(fr);
    float partner = __shfl_xor(qv, 1);
    q[idx] = (d & 1) ? fmaf(qv, c, partner * sn) : fmaf(qv, c, -partner * sn);
  }
}

// ---------------- causal attention with softclamp + online softmax ----------
// grid (16 pairs, 16 heads); block 256. Block processes row-blocks {p, 31-p}.
__global__ __launch_bounds__(256) void attn_k(
    const float* __restrict__ q, const float* __restrict__ k,
    const float* __restrict__ v, const float* __restrict__ g,
    float* __restrict__ ao) {
  int head = blockIdx.y;
  int hkv = head >> 2;
  int tid = threadIdx.x;
  int tx = tid & 15, ty = tid >> 4;
  __shared__ float qs[64][65];
  __shared__ float kps[64][65];  // k-tile during QK, reused as p-tile for PV
  __shared__ float vs[64][64];
  const float scale = 0.125f;  // dh^-0.5
#pragma unroll 1
  for (int half = 0; half < 2; ++half) {
    int rb = half ? (31 - (int)blockIdx.x) : (int)blockIdx.x;
    int row0 = rb * 64;
    {
      int d = tid & 63, r4 = tid >> 6;
#pragma unroll
      for (int p = 0; p < 16; ++p)
        qs[r4 + p * 4][d] =
            q[(size_t)(row0 + r4 + p * 4) * 1024 + head * 64 + d];
    }
    float m_run[4], l_run[4], o[4][4];
#pragma unroll
    for (int i = 0; i < 4; ++i) {
      m_run[i] = -3.0e38f;
      l_run[i] = 0.f;
#pragma unroll
      for (int j = 0; j < 4; ++j) o[i][j] = 0.f;
    }
    __syncthreads();
#pragma unroll 1
    for (int c = 0; c <= rb; ++c) {
      int kbase = c * 64;
      {
        int d = tid & 63, j4 = tid >> 6;
#pragma unroll
        for (int p = 0; p < 16; ++p) {
          int j = j4 + p * 4;
          size_t src = (size_t)(kbase + j) * 256 + hkv * 64 + d;
          kps[j][d] = k[src];
          vs[j][d] = v[src];
        }
      }
      __syncthreads();
      float sacc[4][4] = {{0.f}};
#pragma unroll 4
      for (int d = 0; d < 64; ++d) {
        float a[4], b[4];
#pragma unroll
        for (int i = 0; i < 4; ++i) a[i] = qs[ty * 4 + i][d];
#pragma unroll
        for (int j = 0; j < 4; ++j) b[j] = kps[tx * 4 + j][d];
#pragma unroll
        for (int i = 0; i < 4; ++i)
#pragma unroll
          for (int j = 0; j < 4; ++j) sacc[i][j] += a[i] * b[j];
      }
      // softclamp + causal mask + online softmax (registers + shuffles only)
      float pv[4][4];
#pragma unroll
      for (int i = 0; i < 4; ++i) {
        int rglob = row0 + ty * 4 + i;
        float mt = -3.0e38f;
#pragma unroll
        for (int j = 0; j < 4; ++j) {
          int kglob = kbase + tx * 4 + j;
          float sv = sacc[i][j] * scale;
          float e = __expf(sv * 0.04f);          // 2*(sv/50)
          sv = 50.f * (1.f - 2.f / (e + 1.f));   // 50*tanh(sv/50), inf-safe
          if (kglob > rglob) sv = -3.0e38f;
          pv[i][j] = sv;
          mt = fmaxf(mt, sv);
        }
#pragma unroll
        for (int off = 1; off < 16; off <<= 1)
          mt = fmaxf(mt, __shfl_xor(mt, off));
        float mn = fmaxf(m_run[i], mt);
        float alpha = __expf(m_run[i] - mn);
        float rsum = 0.f;
#pragma unroll
        for (int j = 0; j < 4; ++j) {
          float p = (pv[i][j] < -1.0e37f) ? 0.f : __expf(pv[i][j] - mn);
          pv[i][j] = p;
          rsum += p;
        }
#pragma unroll
        for (int off = 1; off < 16; off <<= 1) rsum += __shfl_xor(rsum, off);
        l_run[i] = l_run[i] * alpha + rsum;
        m_run[i] = mn;
#pragma unroll
        for (int j = 0; j < 4; ++j) o[i][j] *= alpha;
      }
      __syncthreads();  // all QK reads of kps complete before overwrite
#pragma unroll
      for (int i = 0; i < 4; ++i)
#pragma unroll
        for (int j = 0; j < 4; ++j) kps[ty * 4 + i][tx * 4 + j] = pv[i][j];
      __syncthreads();  // p-tile ready
#pragma unroll 4
      for (int j = 0; j < 64; ++j) {
        float pj[4], vj[4];
#pragma unroll
        for (int i = 0; i < 4; ++i) pj[i] = kps[ty * 4 + i][j];
#pragma unroll
        for (int jd = 0; jd < 4; ++jd) vj[jd] = vs[j][tx * 4 + jd];
#pragma unroll
        for (int i = 0; i < 4; ++i)
#pragma unroll
          for (int jd = 0; jd < 4; ++jd) o[i][jd] += pj[i] * vj[jd];
      }
      __syncthreads();  // done with kps/vs for this chunk
    }
#pragma unroll
    for (int i = 0; i < 4; ++i) {
      int rglob = row0 + ty * 4 + i;
      float gate = g[rglob * 16 + head];
      float invl = 1.f / l_run[i];
#pragma unroll
      for (int jd = 0; jd < 4; ++jd)
        ao[(size_t)rglob * 1024 + head * 64 + tx * 4 + jd] =
            o[i][jd] * invl * gate;
    }
    __syncthreads();  // before next half restages qs
  }
}

extern "C" void kernel_launch(void* const* d_in, const int* in_sizes, int n_in,
                              void* d_out, int out_size, void* d_ws,
                              size_t ws_size, hipStream_t stream) {
  const float* x = (const float*)d_in[0];
  const int* positions = (const int*)d_in[1];
  // d_in[2] = attn_mask (causal, known analytically -> unused)
  const float* Wq = (const float*)d_in[3];
  const float* Wk = (const float*)d_in[4];
  const float* Wv = (const float*)d_in[5];
  const float* Wo = (const float*)d_in[6];
  const float* Wg = (const float*)d_in[7];
  const float* Wm = (const float*)d_in[8];
  const float* bm = (const float*)d_in[9];
  const float* Wvr = (const float*)d_in[10];
  const float* ksc = (const float*)d_in[11];
  float* out = (float*)d_out;

  float* ws = (float*)d_ws;
  float* q = ws;                      // 2048*1024
  float* k = q + 2048 * 1024;         // 2048*256
  float* v = k + 2048 * 256;          // 2048*256
  float* rv = v + 2048 * 256;         // 2048*256
  float* g = rv + 2048 * 256;         // 2048*16
  float* ao = g + 2048 * 16;          // 2048*1024  (total ~23.2 MB)

  dim3 blk(256);
  gemm_f32_k<<<dim3(16, 32), blk, 0, stream>>>(x, Wq, q, 2048, 1024, 1024);
  gemm_f32_k<<<dim3(4, 32), blk, 0, stream>>>(x, Wk, k, 2048, 256, 1024);
  gemm_f32_k<<<dim3(4, 32), blk, 0, stream>>>(x, Wv, v, 2048, 256, 1024);
  gemm_f32_k<<<dim3(4, 32), blk, 0, stream>>>(x, Wvr, rv, 2048, 256, 1024);
  postproc_k<<<dim3(2048), blk, 0, stream>>>(x, positions, Wg, Wm, bm, ksc, q,
                                             k, v, rv, g);
  attn_k<<<dim3(16, 16), blk, 0, stream>>>(q, k, v, g, ao);
  gemm_f32_k<<<dim3(16, 32), blk, 0, stream>>>(ao, Wo, out, 2048, 1024, 1024);
}

// Round 2
// 452.248 us; speedup vs baseline: 1.4592x; 1.4592x over previous
//
#include <hip/hip_runtime.h>
#include <hip/hip_bf16.h>
#include <math.h>

typedef unsigned short u16;
typedef unsigned int u32;
typedef __attribute__((ext_vector_type(8))) __bf16 bf16x8;
typedef __attribute__((ext_vector_type(4))) float f32x4;

__device__ inline u16 f2bf(float f) {
  u32 b = __float_as_uint(f);
  b += 0x7FFFu + ((b >> 16) & 1u);
  return (u16)(b >> 16);
}

// ---------------- f32 -> bf16 elementwise convert (n multiple of 2048) ------
__global__ __launch_bounds__(256) void cvt_bf16_k(
    const float* __restrict__ in, u16* __restrict__ out) {
  int i = (blockIdx.x * 256 + threadIdx.x) * 8;
  float4 v0 = *(const float4*)&in[i];
  float4 v1 = *(const float4*)&in[i + 4];
  uint4 pk;
  pk.x = (u32)f2bf(v0.x) | ((u32)f2bf(v0.y) << 16);
  pk.y = (u32)f2bf(v0.z) | ((u32)f2bf(v0.w) << 16);
  pk.z = (u32)f2bf(v1.x) | ((u32)f2bf(v1.y) << 16);
  pk.w = (u32)f2bf(v1.z) | ((u32)f2bf(v1.w) << 16);
  *(uint4*)&out[i] = pk;
}

// ------------- W [K][N] f32 -> Wt [N][K] bf16 ; grid (N/32, K/32), blk(32,8)
__global__ __launch_bounds__(256) void transpose_cvt_k(
    const float* __restrict__ W, u16* __restrict__ Wt, int K, int N) {
  __shared__ float tile[32][33];
  int n0 = blockIdx.x * 32, k0 = blockIdx.y * 32;
  int tx = threadIdx.x, ty = threadIdx.y;
#pragma unroll
  for (int j = 0; j < 4; ++j)
    tile[ty * 4 + j][tx] = W[(size_t)(k0 + ty * 4 + j) * N + n0 + tx];
  __syncthreads();
#pragma unroll
  for (int j = 0; j < 4; ++j)
    Wt[(size_t)(n0 + ty * 4 + j) * K + k0 + tx] = f2bf(tile[tx][ty * 4 + j]);
}

// ---------------- bf16 MFMA GEMM: C[M,N] = A[M,K] @ Bt[N,K]^T, C f32 --------
// tile 128x128, BK=64, 256 threads = 4 waves (2x2 of 64x64)
__global__ __launch_bounds__(256) void gemm_bf16_k(
    const u16* __restrict__ A, const u16* __restrict__ Bt,
    float* __restrict__ C, int M, int N, int K) {
  __shared__ __align__(16) u16 As[128 * 64];
  __shared__ __align__(16) u16 Bs[128 * 64];
  int tid = threadIdx.x;
  int w = tid >> 6, l = tid & 63;
  int wr = w >> 1, wc = w & 1;
  int lr = l & 15, lg = l >> 4;
  int m0 = blockIdx.y * 128, n0 = blockIdx.x * 128;
  f32x4 zero = {0.f, 0.f, 0.f, 0.f};
  f32x4 acc[4][4];
#pragma unroll
  for (int mi = 0; mi < 4; ++mi)
#pragma unroll
    for (int ni = 0; ni < 4; ++ni) acc[mi][ni] = zero;

  for (int kt = 0; kt < K; kt += 64) {
    __syncthreads();
#pragma unroll
    for (int c = 0; c < 4; ++c) {
      int idx = c * 256 + tid;          // 0..1023, 8 bf16 each
      int row = idx >> 3, k0 = (idx & 7) * 8;
      *(uint4*)&As[row * 64 + k0] =
          *(const uint4*)&A[(size_t)(m0 + row) * K + kt + k0];
      *(uint4*)&Bs[row * 64 + k0] =
          *(const uint4*)&Bt[(size_t)(n0 + row) * K + kt + k0];
    }
    __syncthreads();
#pragma unroll
    for (int kw = 0; kw < 2; ++kw) {
      bf16x8 af[4], bfr[4];
#pragma unroll
      for (int i = 0; i < 4; ++i) {
        af[i] = *(const bf16x8*)&As[(wr * 64 + i * 16 + lr) * 64 + kw * 32 + lg * 8];
        bfr[i] = *(const bf16x8*)&Bs[(wc * 64 + i * 16 + lr) * 64 + kw * 32 + lg * 8];
      }
#pragma unroll
      for (int mi = 0; mi < 4; ++mi)
#pragma unroll
        for (int ni = 0; ni < 4; ++ni)
          acc[mi][ni] = __builtin_amdgcn_mfma_f32_16x16x32_bf16(
              af[mi], bfr[ni], acc[mi][ni], 0, 0, 0);
    }
  }
#pragma unroll
  for (int mi = 0; mi < 4; ++mi)
#pragma unroll
    for (int ni = 0; ni < 4; ++ni)
#pragma unroll
      for (int r = 0; r < 4; ++r) {
        int row = m0 + wr * 64 + mi * 16 + lg * 4 + r;
        int col = n0 + wc * 64 + ni * 16 + lr;
        C[(size_t)row * N + col] = acc[mi][ni][r];
      }
}

// ---------------- postprocess on fused QKVR buffer (stride 1792) ------------
// layout per row: [0,1024)=q, [1024,1280)=k, [1280,1536)=v, [1536,1792)=rv
__global__ __launch_bounds__(256) void postproc_k(
    const float* __restrict__ x, const int* __restrict__ positions,
    const float* __restrict__ Wg, const float* __restrict__ Wm,
    const float* __restrict__ bm, const float* __restrict__ ksc,
    float* __restrict__ qkvr, float* __restrict__ g_out) {
  int s = blockIdx.x;
  int tid = threadIdx.x;
  int lane = tid & 63, w = tid >> 6;
  __shared__ float xs[1024];
  __shared__ float dots[20];
  {
    const float4* xg = (const float4*)(x + (size_t)s * 1024);
    ((float4*)xs)[tid] = xg[tid];
  }
  __syncthreads();
  for (int j = w; j < 20; j += 4) {
    const float* W;
    int ldw;
    if (j < 16) { W = Wg + j; ldw = 16; } else { W = Wm + (j - 16); ldw = 4; }
    float p = 0.f;
#pragma unroll
    for (int d0 = 0; d0 < 16; ++d0) {
      int d = d0 * 64 + lane;
      p += xs[d] * W[(size_t)d * ldw];
    }
#pragma unroll
    for (int off = 32; off > 0; off >>= 1) p += __shfl_xor(p, off);
    if (lane == 0) dots[j] = p;
  }
  __syncthreads();
  int pos = positions[s];
  const float LOG1E4_OVER_64 = 9.210340371976184f / 64.f;
  float* row = qkvr + (size_t)s * 1792;
  {  // v mix
    int h = w, d = lane;
    float mixv = 1.f / (1.f + __expf(-(dots[16 + h] + bm[h])));
    float vv = row[1280 + h * 64 + d];
    float rv = row[1536 + h * 64 + d];
    row[1280 + h * 64 + d] = vv + mixv * (rv - vv);
  }
  if (tid < 16) g_out[s * 16 + tid] = 1.f / (1.f + __expf(-dots[tid]));
  {  // k: RMSNorm * k_scale + RoPE
    int h = w, d = lane;
    float kv = row[1024 + h * 64 + d];
    float ss = kv * kv;
#pragma unroll
    for (int off = 32; off > 0; off >>= 1) ss += __shfl_xor(ss, off);
    float rms = sqrtf(ss * (1.f / 64.f) + 1e-8f);
    float kn = kv / rms * ksc[h * 64 + d];
    float fr = (float)pos * __expf(-(float)(d & ~1) * LOG1E4_OVER_64);
    float c = cosf(fr), sn = sinf(fr);
    float partner = __shfl_xor(kn, 1);
    row[1024 + h * 64 + d] =
        (d & 1) ? fmaf(kn, c, partner * sn) : fmaf(kn, c, -partner * sn);
  }
#pragma unroll
  for (int r = 0; r < 4; ++r) {  // q RoPE
    int e = r * 256 + tid;
    int d = e & 63;
    float qv = row[e];
    float fr = (float)pos * __expf(-(float)(d & ~1) * LOG1E4_OVER_64);
    float c = cosf(fr), sn = sinf(fr);
    float partner = __shfl_xor(qv, 1);
    row[e] = (d & 1) ? fmaf(qv, c, partner * sn) : fmaf(qv, c, -partner * sn);
  }
}

// ---------------- causal attention, transposed-vectorized LDS ---------------
// grid (32, 16): bx -> rb = 31-bx (heavy first), by = head. 256 threads.
#define PAD 68
__global__ __launch_bounds__(256) void attn_k(
    const float* __restrict__ qkvr, const float* __restrict__ g,
    u16* __restrict__ aob) {
  int head = blockIdx.y;
  int hkv = head >> 2;
  int rb = 31 - (int)blockIdx.x;
  int row0 = rb * 64;
  int tid = threadIdx.x;
  int tx = tid & 15, ty = tid >> 4;
  __shared__ float qsT[64 * PAD];   // [d][qrow]
  __shared__ float kpsT[64 * PAD];  // [d][key] during QK, [key][qrow] for P
  __shared__ float vs[64 * PAD];    // [key][d]
  const float scale = 0.125f;
  {  // stage q transposed (once per block)
    int r = tid >> 2, d0 = (tid & 3) * 16;
    const float* qrow = qkvr + (size_t)(row0 + r) * 1792 + head * 64;
#pragma unroll
    for (int jj = 0; jj < 4; ++jj) {
      float4 v4 = *(const float4*)&qrow[d0 + jj * 4];
      qsT[(d0 + jj * 4 + 0) * PAD + r] = v4.x;
      qsT[(d0 + jj * 4 + 1) * PAD + r] = v4.y;
      qsT[(d0 + jj * 4 + 2) * PAD + r] = v4.z;
      qsT[(d0 + jj * 4 + 3) * PAD + r] = v4.w;
    }
  }
  float m_run[4], l_run[4], o[4][4];
#pragma unroll
  for (int i = 0; i < 4; ++i) {
    m_run[i] = -3.0e38f;
    l_run[i] = 0.f;
#pragma unroll
    for (int j = 0; j < 4; ++j) o[i][j] = 0.f;
  }
  __syncthreads();
#pragma unroll 1
  for (int c = 0; c <= rb; ++c) {
    int kbase = c * 64;
    {  // stage k transposed + v straight
      int key = tid >> 2, d0 = (tid & 3) * 16;
      const float* krow = qkvr + (size_t)(kbase + key) * 1792 + 1024 + hkv * 64;
      const float* vrow = krow + 256;
#pragma unroll
      for (int jj = 0; jj < 4; ++jj) {
        float4 kv = *(const float4*)&krow[d0 + jj * 4];
        kpsT[(d0 + jj * 4 + 0) * PAD + key] = kv.x;
        kpsT[(d0 + jj * 4 + 1) * PAD + key] = kv.y;
        kpsT[(d0 + jj * 4 + 2) * PAD + key] = kv.z;
        kpsT[(d0 + jj * 4 + 3) * PAD + key] = kv.w;
        *(float4*)&vs[key * PAD + d0 + jj * 4] = *(const float4*)&vrow[d0 + jj * 4];
      }
    }
    __syncthreads();
    float sacc[4][4] = {{0.f}};
#pragma unroll 4
    for (int d = 0; d < 64; ++d) {
      float4 a = *(const float4*)&qsT[d * PAD + ty * 4];
      float4 b = *(const float4*)&kpsT[d * PAD + tx * 4];
      float av[4] = {a.x, a.y, a.z, a.w};
      float bv[4] = {b.x, b.y, b.z, b.w};
#pragma unroll
      for (int i = 0; i < 4; ++i)
#pragma unroll
        for (int j = 0; j < 4; ++j) sacc[i][j] += av[i] * bv[j];
    }
    // softclamp + causal mask + online softmax
    float pv[4][4];
#pragma unroll
    for (int i = 0; i < 4; ++i) {
      int rglob = row0 + ty * 4 + i;
      float mt = -3.0e38f;
#pragma unroll
      for (int j = 0; j < 4; ++j) {
        int kglob = kbase + tx * 4 + j;
        float sv = sacc[i][j] * scale;
        float e = __expf(sv * 0.04f);
        sv = 50.f * (1.f - 2.f / (e + 1.f));
        if (kglob > rglob) sv = -3.0e38f;
        pv[i][j] = sv;
        mt = fmaxf(mt, sv);
      }
#pragma unroll
      for (int off = 1; off < 16; off <<= 1) mt = fmaxf(mt, __shfl_xor(mt, off));
      float mn = fmaxf(m_run[i], mt);
      float alpha = __expf(m_run[i] - mn);
      float rsum = 0.f;
#pragma unroll
      for (int j = 0; j < 4; ++j) {
        float p = (pv[i][j] < -1.0e37f) ? 0.f : __expf(pv[i][j] - mn);
        pv[i][j] = p;
        rsum += p;
      }
#pragma unroll
      for (int off = 1; off < 16; off <<= 1) rsum += __shfl_xor(rsum, off);
      l_run[i] = l_run[i] * alpha + rsum;
      m_run[i] = mn;
#pragma unroll
      for (int j = 0; j < 4; ++j) o[i][j] *= alpha;
    }
    __syncthreads();  // QK reads of kpsT done
#pragma unroll
    for (int i = 0; i < 4; ++i)
#pragma unroll
      for (int j = 0; j < 4; ++j)
        kpsT[(tx * 4 + j) * PAD + ty * 4 + i] = pv[i][j];  // P^T[key][qrow]
    __syncthreads();
#pragma unroll 4
    for (int key = 0; key < 64; ++key) {
      float4 p = *(const float4*)&kpsT[key * PAD + ty * 4];
      float4 vv = *(const float4*)&vs[key * PAD + tx * 4];
      float pj[4] = {p.x, p.y, p.z, p.w};
      float vj[4] = {vv.x, vv.y, vv.z, vv.w};
#pragma unroll
      for (int i = 0; i < 4; ++i)
#pragma unroll
        for (int j = 0; j < 4; ++j) o[i][j] += pj[i] * vj[j];
    }
    __syncthreads();  // done with kpsT/vs this chunk
  }
#pragma unroll
  for (int i = 0; i < 4; ++i) {
    int rglob = row0 + ty * 4 + i;
    float gate = g[rglob * 16 + head];
    float invl = 1.f / l_run[i];
    uint2 pk;
    pk.x = (u32)f2bf(o[i][0] * invl * gate) |
           ((u32)f2bf(o[i][1] * invl * gate) << 16);
    pk.y = (u32)f2bf(o[i][2] * invl * gate) |
           ((u32)f2bf(o[i][3] * invl * gate) << 16);
    *(uint2*)&aob[(size_t)rglob * 1024 + head * 64 + tx * 4] = pk;
  }
}

extern "C" void kernel_launch(void* const* d_in, const int* in_sizes, int n_in,
                              void* d_out, int out_size, void* d_ws,
                              size_t ws_size, hipStream_t stream) {
  const float* x = (const float*)d_in[0];
  const int* positions = (const int*)d_in[1];
  const float* Wq = (const float*)d_in[3];
  const float* Wk = (const float*)d_in[4];
  const float* Wv = (const float*)d_in[5];
  const float* Wo = (const float*)d_in[6];
  const float* Wg = (const float*)d_in[7];
  const float* Wm = (const float*)d_in[8];
  const float* bm = (const float*)d_in[9];
  const float* Wvr = (const float*)d_in[10];
  const float* ksc = (const float*)d_in[11];
  float* out = (float*)d_out;

  // workspace: xb(4MB) | WallT(3.67MB) | qkvr(14.68MB) | g(0.13MB)
  // aob aliases xb (free after gemm1); WoT aliases WallT (free after gemm1)
  u16* xb = (u16*)d_ws;
  u16* WallT = xb + (size_t)2048 * 1024;
  float* qkvr = (float*)(WallT + (size_t)1792 * 1024);
  float* gbuf = qkvr + (size_t)2048 * 1792;
  u16* WoT = WallT;
  u16* aob = xb;

  cvt_bf16_k<<<1024, 256, 0, stream>>>(x, xb);
  transpose_cvt_k<<<dim3(32, 32), dim3(32, 8), 0, stream>>>(Wq, WallT, 1024, 1024);
  transpose_cvt_k<<<dim3(8, 32), dim3(32, 8), 0, stream>>>(Wk, WallT + (size_t)1024 * 1024, 1024, 256);
  transpose_cvt_k<<<dim3(8, 32), dim3(32, 8), 0, stream>>>(Wv, WallT + (size_t)1280 * 1024, 1024, 256);
  transpose_cvt_k<<<dim3(8, 32), dim3(32, 8), 0, stream>>>(Wvr, WallT + (size_t)1536 * 1024, 1024, 256);
  gemm_bf16_k<<<dim3(14, 16), 256, 0, stream>>>(xb, WallT, qkvr, 2048, 1792, 1024);
  postproc_k<<<2048, 256, 0, stream>>>(x, positions, Wg, Wm, bm, ksc, qkvr, gbuf);
  transpose_cvt_k<<<dim3(32, 32), dim3(32, 8), 0, stream>>>(Wo, WoT, 1024, 1024);
  attn_k<<<dim3(32, 16), 256, 0, stream>>>(qkvr, gbuf, aob);
  gemm_bf16_k<<<dim3(8, 16), 256, 0, stream>>>(aob, WoT, out, 2048, 1024, 1024);
}

// Round 3
// 213.915 us; speedup vs baseline: 3.0850x; 2.1142x over previous
//
#include <hip/hip_runtime.h>
#include <hip/hip_bf16.h>
#include <math.h>

typedef unsigned short u16;
typedef unsigned int u32;
typedef __attribute__((ext_vector_type(8))) __bf16 bf16x8;
typedef __attribute__((ext_vector_type(4))) float f32x4;

__device__ inline u16 f2bf(float f) {
  u32 b = __float_as_uint(f);
  b += 0x7FFFu + ((b >> 16) & 1u);
  return (u16)(b >> 16);
}
__device__ inline float bf2f(u16 b) { return __uint_as_float((u32)b << 16); }

// ---------------- f32 -> bf16 elementwise convert -------------------------
__global__ __launch_bounds__(256) void cvt_bf16_k(
    const float* __restrict__ in, u16* __restrict__ out) {
  int i = (blockIdx.x * 256 + threadIdx.x) * 8;
  float4 v0 = *(const float4*)&in[i];
  float4 v1 = *(const float4*)&in[i + 4];
  uint4 pk;
  pk.x = (u32)f2bf(v0.x) | ((u32)f2bf(v0.y) << 16);
  pk.y = (u32)f2bf(v0.z) | ((u32)f2bf(v0.w) << 16);
  pk.z = (u32)f2bf(v1.x) | ((u32)f2bf(v1.y) << 16);
  pk.w = (u32)f2bf(v1.z) | ((u32)f2bf(v1.w) << 16);
  *(uint4*)&out[i] = pk;
}

// ------------- W [K][N] f32 -> Wt [N][K] bf16 ; grid (N/32, K/32), blk(32,8)
__global__ __launch_bounds__(256) void transpose_cvt_k(
    const float* __restrict__ W, u16* __restrict__ Wt, int K, int N) {
  __shared__ float tile[32][33];
  int n0 = blockIdx.x * 32, k0 = blockIdx.y * 32;
  int tx = threadIdx.x, ty = threadIdx.y;
#pragma unroll
  for (int j = 0; j < 4; ++j)
    tile[ty * 4 + j][tx] = W[(size_t)(k0 + ty * 4 + j) * N + n0 + tx];
  __syncthreads();
#pragma unroll
  for (int j = 0; j < 4; ++j)
    Wt[(size_t)(n0 + ty * 4 + j) * K + k0 + tx] = f2bf(tile[tx][ty * 4 + j]);
}

// ---------------- bf16 MFMA GEMM: C[M,N] = A[M,K] @ Bt[N,K]^T ---------------
template <bool BF16_OUT>
__global__ __launch_bounds__(256) void gemm_bf16_k(
    const u16* __restrict__ A, const u16* __restrict__ Bt, void* __restrict__ Cv,
    int M, int N, int K) {
  __shared__ __align__(16) u16 As[128 * 64];
  __shared__ __align__(16) u16 Bs[128 * 64];
  int tid = threadIdx.x;
  int w = tid >> 6, l = tid & 63;
  int wr = w >> 1, wc = w & 1;
  int lr = l & 15, lg = l >> 4;
  int m0 = blockIdx.y * 128, n0 = blockIdx.x * 128;
  f32x4 zero = {0.f, 0.f, 0.f, 0.f};
  f32x4 acc[4][4];
#pragma unroll
  for (int mi = 0; mi < 4; ++mi)
#pragma unroll
    for (int ni = 0; ni < 4; ++ni) acc[mi][ni] = zero;

  for (int kt = 0; kt < K; kt += 64) {
    __syncthreads();
#pragma unroll
    for (int c = 0; c < 4; ++c) {
      int idx = c * 256 + tid;
      int row = idx >> 3, k0 = (idx & 7) * 8;
      *(uint4*)&As[row * 64 + k0] =
          *(const uint4*)&A[(size_t)(m0 + row) * K + kt + k0];
      *(uint4*)&Bs[row * 64 + k0] =
          *(const uint4*)&Bt[(size_t)(n0 + row) * K + kt + k0];
    }
    __syncthreads();
#pragma unroll
    for (int kw = 0; kw < 2; ++kw) {
      bf16x8 af[4], bfr[4];
#pragma unroll
      for (int i = 0; i < 4; ++i) {
        af[i] = *(const bf16x8*)&As[(wr * 64 + i * 16 + lr) * 64 + kw * 32 + lg * 8];
        bfr[i] = *(const bf16x8*)&Bs[(wc * 64 + i * 16 + lr) * 64 + kw * 32 + lg * 8];
      }
#pragma unroll
      for (int mi = 0; mi < 4; ++mi)
#pragma unroll
        for (int ni = 0; ni < 4; ++ni)
          acc[mi][ni] = __builtin_amdgcn_mfma_f32_16x16x32_bf16(
              af[mi], bfr[ni], acc[mi][ni], 0, 0, 0);
    }
  }
#pragma unroll
  for (int mi = 0; mi < 4; ++mi)
#pragma unroll
    for (int ni = 0; ni < 4; ++ni)
#pragma unroll
      for (int r = 0; r < 4; ++r) {
        int row = m0 + wr * 64 + mi * 16 + lg * 4 + r;
        int col = n0 + wc * 64 + ni * 16 + lr;
        if (BF16_OUT)
          ((u16*)Cv)[(size_t)row * N + col] = f2bf(acc[mi][ni][r]);
        else
          ((float*)Cv)[(size_t)row * N + col] = acc[mi][ni][r];
      }
}

// ---------------- postprocess: reads bf16 qkvr, emits bf16 q/k/v ------------
// qkvr row layout (u16): [0,1024)=q, [1024,1280)=k, [1280,1536)=v, [1536,1792)=rv
__global__ __launch_bounds__(256) void postproc_k(
    const float* __restrict__ x, const int* __restrict__ positions,
    const float* __restrict__ Wg, const float* __restrict__ Wm,
    const float* __restrict__ bm, const float* __restrict__ ksc,
    const u16* __restrict__ qkvrb, u16* __restrict__ qb, u16* __restrict__ kb,
    u16* __restrict__ vb, float* __restrict__ g_out) {
  int s = blockIdx.x;
  int tid = threadIdx.x;
  int lane = tid & 63, w = tid >> 6;
  __shared__ float xs[1024];
  __shared__ float dots[20];
  {
    const float4* xg = (const float4*)(x + (size_t)s * 1024);
    ((float4*)xs)[tid] = xg[tid];
  }
  __syncthreads();
  for (int j = w; j < 20; j += 4) {
    const float* W;
    int ldw;
    if (j < 16) { W = Wg + j; ldw = 16; } else { W = Wm + (j - 16); ldw = 4; }
    float p = 0.f;
#pragma unroll
    for (int d0 = 0; d0 < 16; ++d0) {
      int d = d0 * 64 + lane;
      p += xs[d] * W[(size_t)d * ldw];
    }
#pragma unroll
    for (int off = 32; off > 0; off >>= 1) p += __shfl_xor(p, off);
    if (lane == 0) dots[j] = p;
  }
  __syncthreads();
  int pos = positions[s];
  const float LOG1E4_OVER_64 = 9.210340371976184f / 64.f;
  const u16* row = qkvrb + (size_t)s * 1792;
  {  // v mix -> vb [h][s][d]
    int h = w, d = lane;
    float mixv = 1.f / (1.f + __expf(-(dots[16 + h] + bm[h])));
    float vv = bf2f(row[1280 + h * 64 + d]);
    float rv = bf2f(row[1536 + h * 64 + d]);
    vb[((size_t)h * 2048 + s) * 64 + d] = f2bf(vv + mixv * (rv - vv));
  }
  if (tid < 16) g_out[s * 16 + tid] = 1.f / (1.f + __expf(-dots[tid]));
  {  // k: RMSNorm * k_scale + RoPE -> kb [h][s][d]
    int h = w, d = lane;
    float kv = bf2f(row[1024 + h * 64 + d]);
    float ss = kv * kv;
#pragma unroll
    for (int off = 32; off > 0; off >>= 1) ss += __shfl_xor(ss, off);
    float rms = sqrtf(ss * (1.f / 64.f) + 1e-8f);
    float kn = kv / rms * ksc[h * 64 + d];
    float fr = (float)pos * __expf(-(float)(d & ~1) * LOG1E4_OVER_64);
    float c = cosf(fr), sn = sinf(fr);
    float partner = __shfl_xor(kn, 1);
    kb[((size_t)h * 2048 + s) * 64 + d] =
        f2bf((d & 1) ? fmaf(kn, c, partner * sn) : fmaf(kn, c, -partner * sn));
  }
#pragma unroll
  for (int r = 0; r < 4; ++r) {  // q RoPE -> qb [s][qh*dh], pre-scaled
    int e = r * 256 + tid;
    int d = e & 63;
    float qv = bf2f(row[e]);
    float fr = (float)pos * __expf(-(float)(d & ~1) * LOG1E4_OVER_64);
    float c = cosf(fr), sn = sinf(fr);
    float partner = __shfl_xor(qv, 1);
    float qr = (d & 1) ? fmaf(qv, c, partner * sn) : fmaf(qv, c, -partner * sn);
    qb[(size_t)s * 1024 + e] = f2bf(qr * 0.125f);
  }
}

// ---------------- vb [h][s][d] -> vtb [h][d][s] -----------------------------
#define TPAD 66
__global__ __launch_bounds__(256) void vtrans_k(const u16* __restrict__ vb,
                                               u16* __restrict__ vtb) {
  __shared__ u16 tile[64 * TPAD];
  int h = blockIdx.y, s0 = blockIdx.x * 64;
  int t = threadIdx.x;
  {
    int r = t >> 2, cb = (t & 3) * 16;
    const u16* src = vb + ((size_t)h * 2048 + s0 + r) * 64 + cb;
    *(uint4*)&tile[r * TPAD + cb] = *(const uint4*)src;
    *(uint4*)&tile[r * TPAD + cb + 8] = *(const uint4*)(src + 8);
  }
  __syncthreads();
  int d = t >> 2, sb = (t & 3) * 16;
  u16 vals[16];
#pragma unroll
  for (int j = 0; j < 16; ++j) vals[j] = tile[(sb + j) * TPAD + d];
  uint4 a, b;
  a.x = (u32)vals[0] | ((u32)vals[1] << 16);
  a.y = (u32)vals[2] | ((u32)vals[3] << 16);
  a.z = (u32)vals[4] | ((u32)vals[5] << 16);
  a.w = (u32)vals[6] | ((u32)vals[7] << 16);
  b.x = (u32)vals[8] | ((u32)vals[9] << 16);
  b.y = (u32)vals[10] | ((u32)vals[11] << 16);
  b.z = (u32)vals[12] | ((u32)vals[13] << 16);
  b.w = (u32)vals[14] | ((u32)vals[15] << 16);
  u16* dst = vtb + ((size_t)h * 64 + d) * 2048 + s0 + sb;
  *(uint4*)dst = a;
  *(uint4*)(dst + 8) = b;
}

// ---------------- MFMA causal attention -------------------------------------
// grid (16,16): by=head; block handles row-blocks {bx, 31-bx} (33 chunks).
// 4 waves x 16 q-rows. K/V chunk=64 staged in LDS; P via per-wave LDS tile.
#define KPAD 72
__global__ __launch_bounds__(256) void attn_k(
    const u16* __restrict__ qb, const u16* __restrict__ kb,
    const u16* __restrict__ vtb, const float* __restrict__ g,
    u16* __restrict__ aob) {
  __shared__ __align__(16) u16 Ks[64 * KPAD];
  __shared__ __align__(16) u16 Vt[64 * KPAD];
  __shared__ __align__(16) u16 Ps[64 * KPAD];
  int head = blockIdx.y, hkv = head >> 2;
  int tid = threadIdx.x;
  int w = tid >> 6, l = tid & 63;
  int lr = l & 15, lg = l >> 4;
  int skey = tid >> 2;           // staging row (key for Ks, d for Vt)
  int sdb = (tid & 3) * 16;      // staging col offset
  f32x4 zero = {0.f, 0.f, 0.f, 0.f};
#pragma unroll 1
  for (int half = 0; half < 2; ++half) {
    int rb = half ? (31 - (int)blockIdx.x) : (int)blockIdx.x;
    int row0 = rb * 64;
    const u16* qrow = qb + (size_t)(row0 + w * 16 + lr) * 1024 + head * 64;
    bf16x8 qf0 = *(const bf16x8*)&qrow[lg * 8];
    bf16x8 qf1 = *(const bf16x8*)&qrow[32 + lg * 8];
    f32x4 acc_o[4];
    float m_run[4], l_run[4];
#pragma unroll
    for (int r = 0; r < 4; ++r) {
      m_run[r] = -3.0e38f;
      l_run[r] = 0.f;
      acc_o[r] = zero;
    }
    // prefetch chunk 0
    uint4 rk0, rk1, rv0, rv1;
    {
      const u16* kp = kb + ((size_t)hkv * 2048 + skey) * 64 + sdb;
      rk0 = *(const uint4*)kp;
      rk1 = *(const uint4*)(kp + 8);
      const u16* vp = vtb + ((size_t)(hkv * 64 + skey)) * 2048 + sdb;
      rv0 = *(const uint4*)vp;
      rv1 = *(const uint4*)(vp + 8);
    }
#pragma unroll 1
    for (int c = 0; c <= rb; ++c) {
      *(uint4*)&Ks[skey * KPAD + sdb] = rk0;
      *(uint4*)&Ks[skey * KPAD + sdb + 8] = rk1;
      *(uint4*)&Vt[skey * KPAD + sdb] = rv0;
      *(uint4*)&Vt[skey * KPAD + sdb + 8] = rv1;
      __syncthreads();
      if (c < rb) {  // prefetch next chunk during compute
        int nb = (c + 1) * 64;
        const u16* kp = kb + ((size_t)hkv * 2048 + nb + skey) * 64 + sdb;
        rk0 = *(const uint4*)kp;
        rk1 = *(const uint4*)(kp + 8);
        const u16* vp = vtb + ((size_t)(hkv * 64 + skey)) * 2048 + nb + sdb;
        rv0 = *(const uint4*)vp;
        rv1 = *(const uint4*)(vp + 8);
      }
      int kbase = c * 64;
      // QK^T: S 16x64 per wave (f32, scale pre-folded into q)
      f32x4 sa[4];
#pragma unroll
      for (int ni = 0; ni < 4; ++ni) {
        bf16x8 b0 = *(const bf16x8*)&Ks[(ni * 16 + lr) * KPAD + lg * 8];
        bf16x8 b1 = *(const bf16x8*)&Ks[(ni * 16 + lr) * KPAD + 32 + lg * 8];
        f32x4 s = __builtin_amdgcn_mfma_f32_16x16x32_bf16(qf0, b0, zero, 0, 0, 0);
        sa[ni] = __builtin_amdgcn_mfma_f32_16x16x32_bf16(qf1, b1, s, 0, 0, 0);
      }
      bool diag = (c == rb);
      float pv[4][4];
#pragma unroll
      for (int r = 0; r < 4; ++r) {
        int qglob = row0 + w * 16 + lg * 4 + r;
        float mt = -3.0e38f;
#pragma unroll
        for (int ni = 0; ni < 4; ++ni) {
          float sv = sa[ni][r];
          float e = __expf(sv * 0.04f);
          sv = 50.f - 100.f / (e + 1.f);  // 50*tanh(sv/50)
          if (diag && (kbase + ni * 16 + lr) > qglob) sv = -3.0e38f;
          pv[r][ni] = sv;
          mt = fmaxf(mt, sv);
        }
#pragma unroll
        for (int off = 1; off < 16; off <<= 1)
          mt = fmaxf(mt, __shfl_xor(mt, off));
        float mn = fmaxf(m_run[r], mt);
        float alpha = __expf(m_run[r] - mn);
        float rs = 0.f;
#pragma unroll
        for (int ni = 0; ni < 4; ++ni) {
          float p = (pv[r][ni] < -1.0e37f) ? 0.f : __expf(pv[r][ni] - mn);
          pv[r][ni] = p;
          rs += p;
        }
#pragma unroll
        for (int off = 1; off < 16; off <<= 1) rs += __shfl_xor(rs, off);
        l_run[r] = l_run[r] * alpha + rs;
        m_run[r] = mn;
#pragma unroll
        for (int nd = 0; nd < 4; ++nd) acc_o[nd][r] *= alpha;
      }
      // P -> per-wave LDS tile (bf16, A-fragment layout source)
#pragma unroll
      for (int r = 0; r < 4; ++r)
#pragma unroll
        for (int ni = 0; ni < 4; ++ni)
          Ps[(w * 16 + lg * 4 + r) * KPAD + ni * 16 + lr] = f2bf(pv[r][ni]);
      // PV (wave-private Ps: in-order LDS, no barrier needed)
      bf16x8 pf0 = *(const bf16x8*)&Ps[(w * 16 + lr) * KPAD + lg * 8];
      bf16x8 pf1 = *(const bf16x8*)&Ps[(w * 16 + lr) * KPAD + 32 + lg * 8];
#pragma unroll
      for (int nd = 0; nd < 4; ++nd) {
        bf16x8 v0 = *(const bf16x8*)&Vt[(nd * 16 + lr) * KPAD + lg * 8];
        bf16x8 v1 = *(const bf16x8*)&Vt[(nd * 16 + lr) * KPAD + 32 + lg * 8];
        acc_o[nd] = __builtin_amdgcn_mfma_f32_16x16x32_bf16(pf0, v0, acc_o[nd], 0, 0, 0);
        acc_o[nd] = __builtin_amdgcn_mfma_f32_16x16x32_bf16(pf1, v1, acc_o[nd], 0, 0, 0);
      }
      __syncthreads();
    }
#pragma unroll
    for (int r = 0; r < 4; ++r) {
      int row = row0 + w * 16 + lg * 4 + r;
      float sc = (1.f / l_run[r]) * g[row * 16 + head];
#pragma unroll
      for (int nd = 0; nd < 4; ++nd)
        aob[(size_t)row * 1024 + head * 64 + nd * 16 + lr] =
            f2bf(acc_o[nd][r] * sc);
    }
  }
}

extern "C" void kernel_launch(void* const* d_in, const int* in_sizes, int n_in,
                              void* d_out, int out_size, void* d_ws,
                              size_t ws_size, hipStream_t stream) {
  const float* x = (const float*)d_in[0];
  const int* positions = (const int*)d_in[1];
  const float* Wq = (const float*)d_in[3];
  const float* Wk = (const float*)d_in[4];
  const float* Wv = (const float*)d_in[5];
  const float* Wo = (const float*)d_in[6];
  const float* Wg = (const float*)d_in[7];
  const float* Wm = (const float*)d_in[8];
  const float* bm = (const float*)d_in[9];
  const float* Wvr = (const float*)d_in[10];
  const float* ksc = (const float*)d_in[11];
  float* out = (float*)d_out;

  // ws (u16 units): xb 2M | WallT 1.75M | qkvrb 3.5M | qb 2M | kb/vb/vtb 0.5M*3 | gbuf
  u16* xb = (u16*)d_ws;
  u16* WallT = xb + (size_t)2048 * 1024;
  u16* qkvrb = WallT + (size_t)1792 * 1024;
  u16* qbuf = qkvrb + (size_t)2048 * 1792;
  u16* kbuf = qbuf + (size_t)2048 * 1024;
  u16* vbuf = kbuf + (size_t)4 * 2048 * 64;
  u16* vtb = vbuf + (size_t)4 * 2048 * 64;
  float* gbuf = (float*)(vtb + (size_t)4 * 2048 * 64);
  u16* WoT = WallT;  // reuse after gemm1
  u16* aob = xb;     // reuse after gemm1

  cvt_bf16_k<<<1024, 256, 0, stream>>>(x, xb);
  transpose_cvt_k<<<dim3(32, 32), dim3(32, 8), 0, stream>>>(Wq, WallT, 1024, 1024);
  transpose_cvt_k<<<dim3(8, 32), dim3(32, 8), 0, stream>>>(Wk, WallT + (size_t)1024 * 1024, 1024, 256);
  transpose_cvt_k<<<dim3(8, 32), dim3(32, 8), 0, stream>>>(Wv, WallT + (size_t)1280 * 1024, 1024, 256);
  transpose_cvt_k<<<dim3(8, 32), dim3(32, 8), 0, stream>>>(Wvr, WallT + (size_t)1536 * 1024, 1024, 256);
  gemm_bf16_k<true><<<dim3(14, 16), 256, 0, stream>>>(xb, WallT, qkvrb, 2048, 1792, 1024);
  postproc_k<<<2048, 256, 0, stream>>>(x, positions, Wg, Wm, bm, ksc, qkvrb,
                                       qbuf, kbuf, vbuf, gbuf);
  vtrans_k<<<dim3(32, 4), 256, 0, stream>>>(vbuf, vtb);
  transpose_cvt_k<<<dim3(32, 32), dim3(32, 8), 0, stream>>>(Wo, WoT, 1024, 1024);
  attn_k<<<dim3(16, 16), 256, 0, stream>>>(qbuf, kbuf, vtb, gbuf, aob);
  gemm_bf16_k<false><<<dim3(8, 16), 256, 0, stream>>>(aob, WoT, out, 2048, 1024, 1024);
}

// Round 4
// 179.938 us; speedup vs baseline: 3.6675x; 1.1888x over previous
//
#include <hip/hip_runtime.h>
#include <hip/hip_bf16.h>
#include <math.h>

typedef unsigned short u16;
typedef unsigned int u32;
typedef __attribute__((ext_vector_type(8))) __bf16 bf16x8;
typedef __attribute__((ext_vector_type(4))) float f32x4;

__device__ inline u16 f2bf(float f) {
  u32 b = __float_as_uint(f);
  b += 0x7FFFu + ((b >> 16) & 1u);
  return (u16)(b >> 16);
}
__device__ inline float bf2f(u16 b) { return __uint_as_float((u32)b << 16); }

// ---------------- f32 -> bf16 elementwise convert -------------------------
__global__ __launch_bounds__(256) void cvt_bf16_k(
    const float* __restrict__ in, u16* __restrict__ out) {
  int i = (blockIdx.x * 256 + threadIdx.x) * 8;
  float4 v0 = *(const float4*)&in[i];
  float4 v1 = *(const float4*)&in[i + 4];
  uint4 pk;
  pk.x = (u32)f2bf(v0.x) | ((u32)f2bf(v0.y) << 16);
  pk.y = (u32)f2bf(v0.z) | ((u32)f2bf(v0.w) << 16);
  pk.z = (u32)f2bf(v1.x) | ((u32)f2bf(v1.y) << 16);
  pk.w = (u32)f2bf(v1.z) | ((u32)f2bf(v1.w) << 16);
  *(uint4*)&out[i] = pk;
}

// ------------- all weight transposes fused: grid (32, 88), block (32,8) ----
// y-tile n0: [0,1024) Wq | [1024,1280) Wk | [1280,1536) Wv | [1536,1792) Wvr
// -> WallT[n][k]; [1792,2816) Wo -> WoT[n-1792][k]
__global__ __launch_bounds__(256) void prep_w_k(
    const float* __restrict__ Wq, const float* __restrict__ Wk,
    const float* __restrict__ Wv, const float* __restrict__ Wvr,
    const float* __restrict__ Wo, u16* __restrict__ WallT,
    u16* __restrict__ WoT) {
  __shared__ float tile[32][33];
  int k0 = blockIdx.x * 32;
  int n0 = blockIdx.y * 32;
  const float* src;
  int scol, sN;
  u16* dst;
  int drow;
  if (n0 < 1024) { src = Wq; scol = n0; sN = 1024; dst = WallT; drow = n0; }
  else if (n0 < 1280) { src = Wk; scol = n0 - 1024; sN = 256; dst = WallT; drow = n0; }
  else if (n0 < 1536) { src = Wv; scol = n0 - 1280; sN = 256; dst = WallT; drow = n0; }
  else if (n0 < 1792) { src = Wvr; scol = n0 - 1536; sN = 256; dst = WallT; drow = n0; }
  else { src = Wo; scol = n0 - 1792; sN = 1024; dst = WoT; drow = n0 - 1792; }
  int tx = threadIdx.x, ty = threadIdx.y;
#pragma unroll
  for (int j = 0; j < 4; ++j)
    tile[ty * 4 + j][tx] = src[(size_t)(k0 + ty * 4 + j) * sN + scol + tx];
  __syncthreads();
#pragma unroll
  for (int j = 0; j < 4; ++j)
    dst[(size_t)(drow + ty * 4 + j) * 1024 + k0 + tx] = f2bf(tile[tx][ty * 4 + j]);
}

// ---------------- bf16 MFMA GEMM: C[M,N] = A[M,K] @ Bt[N,K]^T ---------------
// 512 threads = 8 waves (2 row-groups x 4 col-groups); tile BM x 128, BK=64
template <int BM, bool BF16_OUT>
__global__ __launch_bounds__(512) void gemm_bf16_k(
    const u16* __restrict__ A, const u16* __restrict__ Bt, void* __restrict__ Cv,
    int M, int N, int K) {
  constexpr int MI = BM / 32;
  __shared__ __align__(16) u16 As[BM * 64];
  __shared__ __align__(16) u16 Bs[128 * 64];
  int tid = threadIdx.x;
  int w = tid >> 6, l = tid & 63;
  int wr = w >> 2, wc = w & 3;
  int lr = l & 15, lg = l >> 4;
  int m0 = blockIdx.y * BM, n0 = blockIdx.x * 128;
  f32x4 zero = {0.f, 0.f, 0.f, 0.f};
  f32x4 acc[MI][2];
#pragma unroll
  for (int mi = 0; mi < MI; ++mi)
#pragma unroll
    for (int ni = 0; ni < 2; ++ni) acc[mi][ni] = zero;

  for (int kt = 0; kt < K; kt += 64) {
    __syncthreads();
#pragma unroll
    for (int c = 0; c < BM * 64 / (8 * 512); ++c) {
      int idx = c * 512 + tid;
      int row = idx >> 3, k0 = (idx & 7) * 8;
      *(uint4*)&As[row * 64 + k0] =
          *(const uint4*)&A[(size_t)(m0 + row) * K + kt + k0];
    }
#pragma unroll
    for (int c = 0; c < 2; ++c) {
      int idx = c * 512 + tid;
      int row = idx >> 3, k0 = (idx & 7) * 8;
      *(uint4*)&Bs[row * 64 + k0] =
          *(const uint4*)&Bt[(size_t)(n0 + row) * K + kt + k0];
    }
    __syncthreads();
#pragma unroll
    for (int kw = 0; kw < 2; ++kw) {
      bf16x8 af[MI], bfr[2];
#pragma unroll
      for (int mi = 0; mi < MI; ++mi)
        af[mi] = *(const bf16x8*)&As[(wr * (BM / 2) + mi * 16 + lr) * 64 + kw * 32 + lg * 8];
#pragma unroll
      for (int ni = 0; ni < 2; ++ni)
        bfr[ni] = *(const bf16x8*)&Bs[(wc * 32 + ni * 16 + lr) * 64 + kw * 32 + lg * 8];
#pragma unroll
      for (int mi = 0; mi < MI; ++mi)
#pragma unroll
        for (int ni = 0; ni < 2; ++ni)
          acc[mi][ni] = __builtin_amdgcn_mfma_f32_16x16x32_bf16(
              af[mi], bfr[ni], acc[mi][ni], 0, 0, 0);
    }
  }
#pragma unroll
  for (int mi = 0; mi < MI; ++mi)
#pragma unroll
    for (int ni = 0; ni < 2; ++ni)
#pragma unroll
      for (int r = 0; r < 4; ++r) {
        int row = m0 + wr * (BM / 2) + mi * 16 + lg * 4 + r;
        int col = n0 + wc * 32 + ni * 16 + lr;
        if (BF16_OUT)
          ((u16*)Cv)[(size_t)row * N + col] = f2bf(acc[mi][ni][r]);
        else
          ((float*)Cv)[(size_t)row * N + col] = acc[mi][ni][r];
      }
}

// ---------------- postprocess: q RoPE in-place, k/v to separate bufs --------
// qkvrb row (u16): [0,1024)=q, [1024,1280)=k, [1280,1536)=v, [1536,1792)=rv
__global__ __launch_bounds__(256) void postproc_k(
    const float* __restrict__ x, const int* __restrict__ positions,
    const float* __restrict__ Wg, const float* __restrict__ Wm,
    const float* __restrict__ bm, const float* __restrict__ ksc,
    u16* __restrict__ qkvrb, u16* __restrict__ kb, u16* __restrict__ vb,
    float* __restrict__ g_out) {
  int s = blockIdx.x;
  int tid = threadIdx.x;
  int lane = tid & 63, w = tid >> 6;
  __shared__ float xs[1024];
  __shared__ float dots[20];
  {
    const float4* xg = (const float4*)(x + (size_t)s * 1024);
    ((float4*)xs)[tid] = xg[tid];
  }
  __syncthreads();
  for (int j = w; j < 20; j += 4) {
    const float* W;
    int ldw;
    if (j < 16) { W = Wg + j; ldw = 16; } else { W = Wm + (j - 16); ldw = 4; }
    float p = 0.f;
#pragma unroll
    for (int d0 = 0; d0 < 16; ++d0) {
      int d = d0 * 64 + lane;
      p += xs[d] * W[(size_t)d * ldw];
    }
#pragma unroll
    for (int off = 32; off > 0; off >>= 1) p += __shfl_xor(p, off);
    if (lane == 0) dots[j] = p;
  }
  __syncthreads();
  int pos = positions[s];
  const float LOG1E4_OVER_64 = 9.210340371976184f / 64.f;
  u16* row = qkvrb + (size_t)s * 1792;
  {  // v mix -> vb [h][s][d]
    int h = w, d = lane;
    float mixv = 1.f / (1.f + __expf(-(dots[16 + h] + bm[h])));
    float vv = bf2f(row[1280 + h * 64 + d]);
    float rv = bf2f(row[1536 + h * 64 + d]);
    vb[((size_t)h * 2048 + s) * 64 + d] = f2bf(vv + mixv * (rv - vv));
  }
  if (tid < 16) g_out[s * 16 + tid] = 1.f / (1.f + __expf(-dots[tid]));
  {  // k: RMSNorm * k_scale + RoPE -> kb [h][s][d]
    int h = w, d = lane;
    float kv = bf2f(row[1024 + h * 64 + d]);
    float ss = kv * kv;
#pragma unroll
    for (int off = 32; off > 0; off >>= 1) ss += __shfl_xor(ss, off);
    float rms = sqrtf(ss * (1.f / 64.f) + 1e-8f);
    float kn = kv / rms * ksc[h * 64 + d];
    float fr = (float)pos * __expf(-(float)(d & ~1) * LOG1E4_OVER_64);
    float c = cosf(fr), sn = sinf(fr);
    float partner = __shfl_xor(kn, 1);
    kb[((size_t)h * 2048 + s) * 64 + d] =
        f2bf((d & 1) ? fmaf(kn, c, partner * sn) : fmaf(kn, c, -partner * sn));
  }
#pragma unroll
  for (int r = 0; r < 4; ++r) {  // q RoPE in-place, pre-scaled by 0.125
    int e = r * 256 + tid;
    int d = e & 63;
    float qv = bf2f(row[e]);
    float fr = (float)pos * __expf(-(float)(d & ~1) * LOG1E4_OVER_64);
    float c = cosf(fr), sn = sinf(fr);
    float partner = __shfl_xor(qv, 1);
    float qr = (d & 1) ? fmaf(qv, c, partner * sn) : fmaf(qv, c, -partner * sn);
    row[e] = f2bf(qr * 0.125f);
  }
}

// ---------------- vb [h][s][d] -> vtb [h][d][s] -----------------------------
#define TPAD 66
__global__ __launch_bounds__(256) void vtrans_k(const u16* __restrict__ vb,
                                               u16* __restrict__ vtb) {
  __shared__ u16 tile[64 * TPAD];
  int h = blockIdx.y, s0 = blockIdx.x * 64;
  int t = threadIdx.x;
  {
    int r = t >> 2, cb = (t & 3) * 16;
    const u16* src = vb + ((size_t)h * 2048 + s0 + r) * 64 + cb;
    *(uint4*)&tile[r * TPAD + cb] = *(const uint4*)src;
    *(uint4*)&tile[r * TPAD + cb + 8] = *(const uint4*)(src + 8);
  }
  __syncthreads();
  int d = t >> 2, sb = (t & 3) * 16;
  u16 vals[16];
#pragma unroll
  for (int j = 0; j < 16; ++j) vals[j] = tile[(sb + j) * TPAD + d];
  uint4 a, b;
  a.x = (u32)vals[0] | ((u32)vals[1] << 16);
  a.y = (u32)vals[2] | ((u32)vals[3] << 16);
  a.z = (u32)vals[4] | ((u32)vals[5] << 16);
  a.w = (u32)vals[6] | ((u32)vals[7] << 16);
  b.x = (u32)vals[8] | ((u32)vals[9] << 16);
  b.y = (u32)vals[10] | ((u32)vals[11] << 16);
  b.z = (u32)vals[12] | ((u32)vals[13] << 16);
  b.w = (u32)vals[14] | ((u32)vals[15] << 16);
  u16* dst = vtb + ((size_t)h * 64 + d) * 2048 + s0 + sb;
  *(uint4*)dst = a;
  *(uint4*)(dst + 8) = b;
}

// ---------------- MFMA causal attention, 8 waves, chunk-parity split --------
// grid (16,16): by=head; block does row-blocks {bx, 31-bx}. 512 threads.
// Wave-group 0: even chunks; group 1: odd chunks. Fixed-50 softmax norm
// (softclamp bounds s<=50 -> p=exp(s-50)<=1; partials add directly).
#define KPAD 72
__global__ __launch_bounds__(512) void attn_k(
    const u16* __restrict__ qkvrb, const u16* __restrict__ kb,
    const u16* __restrict__ vtb, const float* __restrict__ g,
    u16* __restrict__ aob) {
  __shared__ __align__(16) u16 smem[27648];  // 55.3 KB
  int head = blockIdx.y, hkv = head >> 2;
  int tid = threadIdx.x;
  int w = tid >> 6, l = tid & 63;
  int grp = w >> 2, wi = w & 3;
  int lr = l & 15, lg = l >> 4;
  int gtid = wi * 64 + l;        // 0..255 within wave-group
  int skey = gtid >> 2;          // staging row (key for Ks, d for Vt)
  int sdb = (gtid & 3) * 16;     // staging col offset
  u16* Ks = smem + grp * 9216;
  u16* Vt = smem + grp * 9216 + 4608;
  u16* Pw = smem + 18432 + w * 1152;  // per-wave 16 x KPAD
  float* mbuf = (float*)smem;         // merge reuse (20.5 KB, Ps untouched)
  f32x4 zero = {0.f, 0.f, 0.f, 0.f};
#pragma unroll 1
  for (int half = 0; half < 2; ++half) {
    int rb = half ? (31 - (int)blockIdx.x) : (int)blockIdx.x;
    int row0 = rb * 64;
    const u16* qrow = qkvrb + (size_t)(row0 + wi * 16 + lr) * 1792 + head * 64;
    bf16x8 qf0 = *(const bf16x8*)&qrow[lg * 8];
    bf16x8 qf1 = *(const bf16x8*)&qrow[32 + lg * 8];
    f32x4 acc_o[4];
    float l_part[4];
#pragma unroll
    for (int r = 0; r < 4; ++r) {
      l_part[r] = 0.f;
      acc_o[r] = zero;
    }
    uint4 rk0, rk1, rv0, rv1;
    int c = grp;
    if (c <= rb) {  // prefetch first chunk of this group
      const u16* kp = kb + ((size_t)hkv * 2048 + c * 64 + skey) * 64 + sdb;
      rk0 = *(const uint4*)kp;
      rk1 = *(const uint4*)(kp + 8);
      const u16* vp = vtb + ((size_t)(hkv * 64 + skey)) * 2048 + c * 64 + sdb;
      rv0 = *(const uint4*)vp;
      rv1 = *(const uint4*)(vp + 8);
    }
    int nit = (rb >> 1) + 1;
#pragma unroll 1
    for (int i = 0; i < nit; ++i, c += 2) {
      bool valid = (c <= rb);
      if (valid) {
        *(uint4*)&Ks[skey * KPAD + sdb] = rk0;
        *(uint4*)&Ks[skey * KPAD + sdb + 8] = rk1;
        *(uint4*)&Vt[skey * KPAD + sdb] = rv0;
        *(uint4*)&Vt[skey * KPAD + sdb + 8] = rv1;
      }
      __syncthreads();
      if (valid && c + 2 <= rb) {  // prefetch next chunk of this group
        int nb = (c + 2) * 64;
        const u16* kp = kb + ((size_t)hkv * 2048 + nb + skey) * 64 + sdb;
        rk0 = *(const uint4*)kp;
        rk1 = *(const uint4*)(kp + 8);
        const u16* vp = vtb + ((size_t)(hkv * 64 + skey)) * 2048 + nb + sdb;
        rv0 = *(const uint4*)vp;
        rv1 = *(const uint4*)(vp + 8);
      }
      if (valid) {
        int kbase = c * 64;
        f32x4 sa[4];
#pragma unroll
        for (int ni = 0; ni < 4; ++ni) {
          bf16x8 b0 = *(const bf16x8*)&Ks[(ni * 16 + lr) * KPAD + lg * 8];
          bf16x8 b1 = *(const bf16x8*)&Ks[(ni * 16 + lr) * KPAD + 32 + lg * 8];
          f32x4 s = __builtin_amdgcn_mfma_f32_16x16x32_bf16(qf0, b0, zero, 0, 0, 0);
          sa[ni] = __builtin_amdgcn_mfma_f32_16x16x32_bf16(qf1, b1, s, 0, 0, 0);
        }
        bool diag = (c == rb);
        float pv[4][4];
#pragma unroll
        for (int r = 0; r < 4; ++r) {
          int qglob = row0 + wi * 16 + lg * 4 + r;
#pragma unroll
          for (int ni = 0; ni < 4; ++ni) {
            float sv = sa[ni][r];
            // p = exp(50*tanh(sv/50) - 50) = exp(-100/(exp(.04*sv)+1))
            float e = __expf(sv * 0.04f);
            float p = __expf(-100.f / (e + 1.f));
            if (diag && (kbase + ni * 16 + lr) > qglob) p = 0.f;
            pv[r][ni] = p;
            l_part[r] += p;
          }
        }
        // P -> per-wave LDS tile (wave-private: no barrier needed)
#pragma unroll
        for (int r = 0; r < 4; ++r)
#pragma unroll
          for (int ni = 0; ni < 4; ++ni)
            Pw[(lg * 4 + r) * KPAD + ni * 16 + lr] = f2bf(pv[r][ni]);
        bf16x8 pf0 = *(const bf16x8*)&Pw[lr * KPAD + lg * 8];
        bf16x8 pf1 = *(const bf16x8*)&Pw[lr * KPAD + 32 + lg * 8];
#pragma unroll
        for (int nd = 0; nd < 4; ++nd) {
          bf16x8 v0 = *(const bf16x8*)&Vt[(nd * 16 + lr) * KPAD + lg * 8];
          bf16x8 v1 = *(const bf16x8*)&Vt[(nd * 16 + lr) * KPAD + 32 + lg * 8];
          acc_o[nd] = __builtin_amdgcn_mfma_f32_16x16x32_bf16(pf0, v0, acc_o[nd], 0, 0, 0);
          acc_o[nd] = __builtin_amdgcn_mfma_f32_16x16x32_bf16(pf1, v1, acc_o[nd], 0, 0, 0);
        }
      }
      __syncthreads();
    }
    // epilogue: reduce l over the 16 lanes of each row, then merge groups
#pragma unroll
    for (int r = 0; r < 4; ++r) {
      float lp = l_part[r];
      lp += __shfl_xor(lp, 1);
      lp += __shfl_xor(lp, 2);
      lp += __shfl_xor(lp, 4);
      lp += __shfl_xor(lp, 8);
      l_part[r] = lp;
    }
    if (grp == 1) {
      float* mb = mbuf + (size_t)(wi * 64 + l) * 20;
#pragma unroll
      for (int nd = 0; nd < 4; ++nd)
#pragma unroll
        for (int r = 0; r < 4; ++r) mb[nd * 4 + r] = acc_o[nd][r];
#pragma unroll
      for (int r = 0; r < 4; ++r) mb[16 + r] = l_part[r];
    }
    __syncthreads();
    if (grp == 0) {
      const float* mb = mbuf + (size_t)(wi * 64 + l) * 20;
#pragma unroll
      for (int r = 0; r < 4; ++r) {
        float lt = l_part[r] + mb[16 + r];
        int row = row0 + wi * 16 + lg * 4 + r;
        float sc = g[row * 16 + head] / lt;
#pragma unroll
        for (int nd = 0; nd < 4; ++nd)
          aob[(size_t)row * 1024 + head * 64 + nd * 16 + lr] =
              f2bf((acc_o[nd][r] + mb[nd * 4 + r]) * sc);
      }
    }
    __syncthreads();
  }
}

extern "C" void kernel_launch(void* const* d_in, const int* in_sizes, int n_in,
                              void* d_out, int out_size, void* d_ws,
                              size_t ws_size, hipStream_t stream) {
  const float* x = (const float*)d_in[0];
  const int* positions = (const int*)d_in[1];
  const float* Wq = (const float*)d_in[3];
  const float* Wk = (const float*)d_in[4];
  const float* Wv = (const float*)d_in[5];
  const float* Wo = (const float*)d_in[6];
  const float* Wg = (const float*)d_in[7];
  const float* Wm = (const float*)d_in[8];
  const float* bm = (const float*)d_in[9];
  const float* Wvr = (const float*)d_in[10];
  const float* ksc = (const float*)d_in[11];
  float* out = (float*)d_out;

  u16* xb = (u16*)d_ws;                           // 2048*1024
  u16* WallT = xb + (size_t)2048 * 1024;          // 1792*1024
  u16* WoT = WallT + (size_t)1792 * 1024;         // 1024*1024
  u16* qkvrb = WoT + (size_t)1024 * 1024;         // 2048*1792
  u16* kbuf = qkvrb + (size_t)2048 * 1792;        // 4*2048*64
  u16* vbuf = kbuf + (size_t)4 * 2048 * 64;
  u16* vtb = vbuf + (size_t)4 * 2048 * 64;
  float* gbuf = (float*)(vtb + (size_t)4 * 2048 * 64);  // 2048*16 f32
  u16* aob = xb;  // xb dead after gemm1

  cvt_bf16_k<<<1024, 256, 0, stream>>>(x, xb);
  prep_w_k<<<dim3(32, 88), dim3(32, 8), 0, stream>>>(Wq, Wk, Wv, Wvr, Wo,
                                                     WallT, WoT);
  gemm_bf16_k<128, true><<<dim3(14, 16), 512, 0, stream>>>(xb, WallT, qkvrb,
                                                           2048, 1792, 1024);
  postproc_k<<<2048, 256, 0, stream>>>(x, positions, Wg, Wm, bm, ksc, qkvrb,
                                       kbuf, vbuf, gbuf);
  vtrans_k<<<dim3(32, 4), 256, 0, stream>>>(vbuf, vtb);
  attn_k<<<dim3(16, 16), 512, 0, stream>>>(qkvrb, kbuf, vtb, gbuf, aob);
  gemm_bf16_k<64, false><<<dim3(8, 32), 512, 0, stream>>>(aob, WoT, out, 2048,
                                                          1024, 1024);
}

// Round 5
// 116.420 us; speedup vs baseline: 5.6685x; 1.5456x over previous
//
#include <hip/hip_runtime.h>
#include <hip/hip_bf16.h>
#include <math.h>

typedef unsigned short u16;
typedef unsigned int u32;
typedef __attribute__((ext_vector_type(8))) __bf16 bf16x8;
typedef __attribute__((ext_vector_type(4))) float f32x4;

__device__ inline u16 f2bf(float f) {
  u32 b = __float_as_uint(f);
  b += 0x7FFFu + ((b >> 16) & 1u);
  return (u16)(b >> 16);
}
__device__ inline float bf2f(u16 b) { return __uint_as_float((u32)b << 16); }

// ---------------- f32 -> bf16 elementwise convert -------------------------
__global__ __launch_bounds__(256) void cvt_bf16_k(
    const float* __restrict__ in, u16* __restrict__ out) {
  int i = (blockIdx.x * 256 + threadIdx.x) * 8;
  float4 v0 = *(const float4*)&in[i];
  float4 v1 = *(const float4*)&in[i + 4];
  uint4 pk;
  pk.x = (u32)f2bf(v0.x) | ((u32)f2bf(v0.y) << 16);
  pk.y = (u32)f2bf(v0.z) | ((u32)f2bf(v0.w) << 16);
  pk.z = (u32)f2bf(v1.x) | ((u32)f2bf(v1.y) << 16);
  pk.w = (u32)f2bf(v1.z) | ((u32)f2bf(v1.w) << 16);
  *(uint4*)&out[i] = pk;
}

// ------------- weight prep: grid (32, 92), block (32,8) --------------------
// y in [0,56): WallT rows y*32 from Wq/Wk/Wv/Wvr (transpose)
// y in [56,60): WallT rows 1792+ : Wg^T (16), Wm^T (4), zeros to 1920
// y in [60,92): WoT rows (y-60)*32 from Wo (transpose)
__global__ __launch_bounds__(256) void prep_w_k(
    const float* __restrict__ Wq, const float* __restrict__ Wk,
    const float* __restrict__ Wv, const float* __restrict__ Wvr,
    const float* __restrict__ Wo, const float* __restrict__ Wg,
    const float* __restrict__ Wm, u16* __restrict__ WallT,
    u16* __restrict__ WoT) {
  __shared__ float tile[32][33];
  int k0 = blockIdx.x * 32;
  int ybl = blockIdx.y;
  int tx = threadIdx.x, ty = threadIdx.y;
  const float* src;
  int scol, sN, drow;
  u16* dst;
  if (ybl >= 60) {
    src = Wo; scol = (ybl - 60) * 32; sN = 1024; dst = WoT; drow = scol;
  } else {
    int n0 = ybl * 32;
    if (n0 >= 1792) {  // Wg/Wm/zero region, direct (no LDS)
#pragma unroll
      for (int j = 0; j < 4; ++j) {
        int n = n0 + ty * 4 + j, j2 = n - 1792, k = k0 + tx;
        float val = (j2 < 16) ? Wg[(size_t)k * 16 + j2]
                  : (j2 < 20) ? Wm[(size_t)k * 4 + (j2 - 16)] : 0.f;
        WallT[(size_t)n * 1024 + k] = f2bf(val);
      }
      return;
    }
    dst = WallT; drow = n0;
    if (n0 < 1024) { src = Wq; scol = n0; sN = 1024; }
    else if (n0 < 1280) { src = Wk; scol = n0 - 1024; sN = 256; }
    else if (n0 < 1536) { src = Wv; scol = n0 - 1280; sN = 256; }
    else { src = Wvr; scol = n0 - 1536; sN = 256; }
  }
#pragma unroll
  for (int j = 0; j < 4; ++j)
    tile[ty * 4 + j][tx] = src[(size_t)(k0 + ty * 4 + j) * sN + scol + tx];
  __syncthreads();
#pragma unroll
  for (int j = 0; j < 4; ++j)
    dst[(size_t)(drow + ty * 4 + j) * 1024 + k0 + tx] = f2bf(tile[tx][ty * 4 + j]);
}

// ------------- RoPE table: tab[s][0:32]=cos, [32:64]=sin --------------------
__global__ __launch_bounds__(256) void rope_tab_k(
    const int* __restrict__ positions, float* __restrict__ tab) {
  int idx = blockIdx.x * 256 + threadIdx.x;  // 65536
  int s = idx >> 5, f = idx & 31;
  float inv = __expf(-(float)f * (9.210340371976184f / 32.f));
  float ang = (float)positions[s] * inv;
  tab[(size_t)s * 64 + f] = cosf(ang);
  tab[(size_t)s * 64 + 32 + f] = sinf(ang);
}

// ---------------- bf16 MFMA GEMM: C[M,N] = A[M,K] @ Bt[N,K]^T ---------------
template <int BM, bool BF16_OUT>
__global__ __launch_bounds__(512) void gemm_bf16_k(
    const u16* __restrict__ A, const u16* __restrict__ Bt, void* __restrict__ Cv,
    int M, int N, int K) {
  constexpr int MI = BM / 32;
  __shared__ __align__(16) u16 As[BM * 64];
  __shared__ __align__(16) u16 Bs[128 * 64];
  int tid = threadIdx.x;
  int w = tid >> 6, l = tid & 63;
  int wr = w >> 2, wc = w & 3;
  int lr = l & 15, lg = l >> 4;
  int m0 = blockIdx.y * BM, n0 = blockIdx.x * 128;
  f32x4 zero = {0.f, 0.f, 0.f, 0.f};
  f32x4 acc[MI][2];
#pragma unroll
  for (int mi = 0; mi < MI; ++mi)
#pragma unroll
    for (int ni = 0; ni < 2; ++ni) acc[mi][ni] = zero;

  for (int kt = 0; kt < K; kt += 64) {
    __syncthreads();
#pragma unroll
    for (int c = 0; c < BM * 64 / (8 * 512); ++c) {
      int idx = c * 512 + tid;
      int row = idx >> 3, k0 = (idx & 7) * 8;
      *(uint4*)&As[row * 64 + k0] =
          *(const uint4*)&A[(size_t)(m0 + row) * K + kt + k0];
    }
#pragma unroll
    for (int c = 0; c < 2; ++c) {
      int idx = c * 512 + tid;
      int row = idx >> 3, k0 = (idx & 7) * 8;
      *(uint4*)&Bs[row * 64 + k0] =
          *(const uint4*)&Bt[(size_t)(n0 + row) * K + kt + k0];
    }
    __syncthreads();
#pragma unroll
    for (int kw = 0; kw < 2; ++kw) {
      bf16x8 af[MI], bfr[2];
#pragma unroll
      for (int mi = 0; mi < MI; ++mi)
        af[mi] = *(const bf16x8*)&As[(wr * (BM / 2) + mi * 16 + lr) * 64 + kw * 32 + lg * 8];
#pragma unroll
      for (int ni = 0; ni < 2; ++ni)
        bfr[ni] = *(const bf16x8*)&Bs[(wc * 32 + ni * 16 + lr) * 64 + kw * 32 + lg * 8];
#pragma unroll
      for (int mi = 0; mi < MI; ++mi)
#pragma unroll
        for (int ni = 0; ni < 2; ++ni)
          acc[mi][ni] = __builtin_amdgcn_mfma_f32_16x16x32_bf16(
              af[mi], bfr[ni], acc[mi][ni], 0, 0, 0);
    }
  }
#pragma unroll
  for (int mi = 0; mi < MI; ++mi)
#pragma unroll
    for (int ni = 0; ni < 2; ++ni)
#pragma unroll
      for (int r = 0; r < 4; ++r) {
        int row = m0 + wr * (BM / 2) + mi * 16 + lg * 4 + r;
        int col = n0 + wc * 32 + ni * 16 + lr;
        if (BF16_OUT)
          ((u16*)Cv)[(size_t)row * N + col] = f2bf(acc[mi][ni][r]);
        else
          ((float*)Cv)[(size_t)row * N + col] = acc[mi][ni][r];
      }
}

// ---------------- postprocess (no LDS, no barriers) -------------------------
// qkvrb row (u16, stride 1920): [0,1024)=q, [1024,1280)=k, [1280,1536)=v,
// [1536,1792)=rv, [1792,1808)=g-dots, [1808,1812)=m-dots
__global__ __launch_bounds__(256) void postproc_k(
    const float* __restrict__ bm, const float* __restrict__ ksc,
    const float* __restrict__ rtab, u16* __restrict__ qkvrb,
    u16* __restrict__ kb, u16* __restrict__ vb, float* __restrict__ g_out) {
  int s = blockIdx.x, tid = threadIdx.x;
  int lane = tid & 63, w = tid >> 6;
  u16* row = qkvrb + (size_t)s * 1920;
  const float* tr = rtab + (size_t)s * 64;
  if (tid < 16)
    g_out[s * 16 + tid] = 1.f / (1.f + __expf(-bf2f(row[1792 + tid])));
  int h = w, d = lane;
  float c = tr[d >> 1], sn = tr[32 + (d >> 1)];
  {  // v mix -> vb [h][s][d]
    float mixv = 1.f / (1.f + __expf(-(bf2f(row[1808 + h]) + bm[h])));
    float vv = bf2f(row[1280 + h * 64 + d]);
    float rv = bf2f(row[1536 + h * 64 + d]);
    vb[((size_t)h * 2048 + s) * 64 + d] = f2bf(vv + mixv * (rv - vv));
  }
  {  // k: RMSNorm * k_scale + RoPE -> kb [h][s][d]
    float kv = bf2f(row[1024 + h * 64 + d]);
    float ss = kv * kv;
#pragma unroll
    for (int off = 32; off > 0; off >>= 1) ss += __shfl_xor(ss, off);
    float rms = sqrtf(ss * (1.f / 64.f) + 1e-8f);
    float kn = kv / rms * ksc[h * 64 + d];
    float partner = __shfl_xor(kn, 1);
    kb[((size_t)h * 2048 + s) * 64 + d] =
        f2bf((d & 1) ? fmaf(kn, c, partner * sn) : fmaf(kn, c, -partner * sn));
  }
#pragma unroll
  for (int r = 0; r < 4; ++r) {  // q RoPE in-place, pre-scaled by 0.125
    int e = r * 256 + tid;
    int dq = e & 63;
    float cq = tr[dq >> 1], sq = tr[32 + (dq >> 1)];
    float qv = bf2f(row[e]);
    float partner = __shfl_xor(qv, 1);
    float qr = (e & 1) ? fmaf(qv, cq, partner * sq) : fmaf(qv, cq, -partner * sq);
    row[e] = f2bf(qr * 0.125f);
  }
}

// ---------------- vb [h][s][d] -> vtb [h][d][s] -----------------------------
#define TPAD 66
__global__ __launch_bounds__(256) void vtrans_k(const u16* __restrict__ vb,
                                               u16* __restrict__ vtb) {
  __shared__ u16 tile[64 * TPAD];
  int h = blockIdx.y, s0 = blockIdx.x * 64;
  int t = threadIdx.x;
  {
    int r = t >> 2, cb = (t & 3) * 16;
    const u16* src = vb + ((size_t)h * 2048 + s0 + r) * 64 + cb;
    *(uint4*)&tile[r * TPAD + cb] = *(const uint4*)src;
    *(uint4*)&tile[r * TPAD + cb + 8] = *(const uint4*)(src + 8);
  }
  __syncthreads();
  int d = t >> 2, sb = (t & 3) * 16;
  u16 vals[16];
#pragma unroll
  for (int j = 0; j < 16; ++j) vals[j] = tile[(sb + j) * TPAD + d];
  uint4 a, b;
  a.x = (u32)vals[0] | ((u32)vals[1] << 16);
  a.y = (u32)vals[2] | ((u32)vals[3] << 16);
  a.z = (u32)vals[4] | ((u32)vals[5] << 16);
  a.w = (u32)vals[6] | ((u32)vals[7] << 16);
  b.x = (u32)vals[8] | ((u32)vals[9] << 16);
  b.y = (u32)vals[10] | ((u32)vals[11] << 16);
  b.z = (u32)vals[12] | ((u32)vals[13] << 16);
  b.w = (u32)vals[14] | ((u32)vals[15] << 16);
  u16* dst = vtb + ((size_t)h * 64 + d) * 2048 + s0 + sb;
  *(uint4*)dst = a;
  *(uint4*)(dst + 8) = b;
}

// ---------------- MFMA causal attention, 8 waves, chunk-parity split --------
#define KPAD 72
__global__ __launch_bounds__(512) void attn_k(
    const u16* __restrict__ qkvrb, const u16* __restrict__ kb,
    const u16* __restrict__ vtb, const float* __restrict__ g,
    u16* __restrict__ aob) {
  __shared__ __align__(16) u16 smem[27648];  // 55.3 KB
  int head = blockIdx.y, hkv = head >> 2;
  int tid = threadIdx.x;
  int w = tid >> 6, l = tid & 63;
  int grp = w >> 2, wi = w & 3;
  int lr = l & 15, lg = l >> 4;
  int gtid = wi * 64 + l;
  int skey = gtid >> 2;
  int sdb = (gtid & 3) * 16;
  u16* Ks = smem + grp * 9216;
  u16* Vt = smem + grp * 9216 + 4608;
  u16* Pw = smem + 18432 + w * 1152;
  float* mbuf = (float*)smem;
  f32x4 zero = {0.f, 0.f, 0.f, 0.f};
#pragma unroll 1
  for (int half = 0; half < 2; ++half) {
    int rb = half ? (31 - (int)blockIdx.x) : (int)blockIdx.x;
    int row0 = rb * 64;
    const u16* qrow = qkvrb + (size_t)(row0 + wi * 16 + lr) * 1920 + head * 64;
    bf16x8 qf0 = *(const bf16x8*)&qrow[lg * 8];
    bf16x8 qf1 = *(const bf16x8*)&qrow[32 + lg * 8];
    f32x4 acc_o[4];
    float l_part[4];
#pragma unroll
    for (int r = 0; r < 4; ++r) {
      l_part[r] = 0.f;
      acc_o[r] = zero;
    }
    uint4 rk0, rk1, rv0, rv1;
    int c = grp;
    if (c <= rb) {
      const u16* kp = kb + ((size_t)hkv * 2048 + c * 64 + skey) * 64 + sdb;
      rk0 = *(const uint4*)kp;
      rk1 = *(const uint4*)(kp + 8);
      const u16* vp = vtb + ((size_t)(hkv * 64 + skey)) * 2048 + c * 64 + sdb;
      rv0 = *(const uint4*)vp;
      rv1 = *(const uint4*)(vp + 8);
    }
    int nit = (rb >> 1) + 1;
#pragma unroll 1
    for (int i = 0; i < nit; ++i, c += 2) {
      bool valid = (c <= rb);
      if (valid) {
        *(uint4*)&Ks[skey * KPAD + sdb] = rk0;
        *(uint4*)&Ks[skey * KPAD + sdb + 8] = rk1;
        *(uint4*)&Vt[skey * KPAD + sdb] = rv0;
        *(uint4*)&Vt[skey * KPAD + sdb + 8] = rv1;
      }
      __syncthreads();
      if (valid && c + 2 <= rb) {
        int nb = (c + 2) * 64;
        const u16* kp = kb + ((size_t)hkv * 2048 + nb + skey) * 64 + sdb;
        rk0 = *(const uint4*)kp;
        rk1 = *(const uint4*)(kp + 8);
        const u16* vp = vtb + ((size_t)(hkv * 64 + skey)) * 2048 + nb + sdb;
        rv0 = *(const uint4*)vp;
        rv1 = *(const uint4*)(vp + 8);
      }
      if (valid) {
        int kbase = c * 64;
        f32x4 sa[4];
#pragma unroll
        for (int ni = 0; ni < 4; ++ni) {
          bf16x8 b0 = *(const bf16x8*)&Ks[(ni * 16 + lr) * KPAD + lg * 8];
          bf16x8 b1 = *(const bf16x8*)&Ks[(ni * 16 + lr) * KPAD + 32 + lg * 8];
          f32x4 s = __builtin_amdgcn_mfma_f32_16x16x32_bf16(qf0, b0, zero, 0, 0, 0);
          sa[ni] = __builtin_amdgcn_mfma_f32_16x16x32_bf16(qf1, b1, s, 0, 0, 0);
        }
        bool diag = (c == rb);
        float pv[4][4];
#pragma unroll
        for (int r = 0; r < 4; ++r) {
          int qglob = row0 + wi * 16 + lg * 4 + r;
#pragma unroll
          for (int ni = 0; ni < 4; ++ni) {
            float sv = sa[ni][r];
            float e = __expf(sv * 0.04f);
            float p = __expf(-100.f / (e + 1.f));
            if (diag && (kbase + ni * 16 + lr) > qglob) p = 0.f;
            pv[r][ni] = p;
            l_part[r] += p;
          }
        }
#pragma unroll
        for (int r = 0; r < 4; ++r)
#pragma unroll
          for (int ni = 0; ni < 4; ++ni)
            Pw[(lg * 4 + r) * KPAD + ni * 16 + lr] = f2bf(pv[r][ni]);
        bf16x8 pf0 = *(const bf16x8*)&Pw[lr * KPAD + lg * 8];
        bf16x8 pf1 = *(const bf16x8*)&Pw[lr * KPAD + 32 + lg * 8];
#pragma unroll
        for (int nd = 0; nd < 4; ++nd) {
          bf16x8 v0 = *(const bf16x8*)&Vt[(nd * 16 + lr) * KPAD + lg * 8];
          bf16x8 v1 = *(const bf16x8*)&Vt[(nd * 16 + lr) * KPAD + 32 + lg * 8];
          acc_o[nd] = __builtin_amdgcn_mfma_f32_16x16x32_bf16(pf0, v0, acc_o[nd], 0, 0, 0);
          acc_o[nd] = __builtin_amdgcn_mfma_f32_16x16x32_bf16(pf1, v1, acc_o[nd], 0, 0, 0);
        }
      }
      __syncthreads();
    }
#pragma unroll
    for (int r = 0; r < 4; ++r) {
      float lp = l_part[r];
      lp += __shfl_xor(lp, 1);
      lp += __shfl_xor(lp, 2);
      lp += __shfl_xor(lp, 4);
      lp += __shfl_xor(lp, 8);
      l_part[r] = lp;
    }
    if (grp == 1) {
      float* mb = mbuf + (size_t)(wi * 64 + l) * 20;
#pragma unroll
      for (int nd = 0; nd < 4; ++nd)
#pragma unroll
        for (int r = 0; r < 4; ++r) mb[nd * 4 + r] = acc_o[nd][r];
#pragma unroll
      for (int r = 0; r < 4; ++r) mb[16 + r] = l_part[r];
    }
    __syncthreads();
    if (grp == 0) {
      const float* mb = mbuf + (size_t)(wi * 64 + l) * 20;
#pragma unroll
      for (int r = 0; r < 4; ++r) {
        float lt = l_part[r] + mb[16 + r];
        int row = row0 + wi * 16 + lg * 4 + r;
        float sc = g[row * 16 + head] / lt;
#pragma unroll
        for (int nd = 0; nd < 4; ++nd)
          aob[(size_t)row * 1024 + head * 64 + nd * 16 + lr] =
              f2bf((acc_o[nd][r] + mb[nd * 4 + r]) * sc);
      }
    }
    __syncthreads();
  }
}

extern "C" void kernel_launch(void* const* d_in, const int* in_sizes, int n_in,
                              void* d_out, int out_size, void* d_ws,
                              size_t ws_size, hipStream_t stream) {
  const float* x = (const float*)d_in[0];
  const int* positions = (const int*)d_in[1];
  const float* Wq = (const float*)d_in[3];
  const float* Wk = (const float*)d_in[4];
  const float* Wv = (const float*)d_in[5];
  const float* Wo = (const float*)d_in[6];
  const float* Wg = (const float*)d_in[7];
  const float* Wm = (const float*)d_in[8];
  const float* bm = (const float*)d_in[9];
  const float* Wvr = (const float*)d_in[10];
  const float* ksc = (const float*)d_in[11];
  float* out = (float*)d_out;

  u16* xb = (u16*)d_ws;                            // 2048*1024
  u16* WallT = xb + (size_t)2048 * 1024;           // 1920*1024
  u16* WoT = WallT + (size_t)1920 * 1024;          // 1024*1024
  u16* qkvrb = WoT + (size_t)1024 * 1024;          // 2048*1920
  u16* kbuf = qkvrb + (size_t)2048 * 1920;         // 4*2048*64
  u16* vbuf = kbuf + (size_t)4 * 2048 * 64;
  u16* vtb = vbuf + (size_t)4 * 2048 * 64;
  float* gbuf = (float*)(vtb + (size_t)4 * 2048 * 64);  // 2048*16 f32
  float* rtab = gbuf + (size_t)2048 * 16;               // 2048*64 f32
  u16* aob = xb;  // xb dead after gemm1

  cvt_bf16_k<<<1024, 256, 0, stream>>>(x, xb);
  prep_w_k<<<dim3(32, 92), dim3(32, 8), 0, stream>>>(Wq, Wk, Wv, Wvr, Wo, Wg,
                                                     Wm, WallT, WoT);
  rope_tab_k<<<256, 256, 0, stream>>>(positions, rtab);
  gemm_bf16_k<128, true><<<dim3(15, 16), 512, 0, stream>>>(xb, WallT, qkvrb,
                                                           2048, 1920, 1024);
  postproc_k<<<2048, 256, 0, stream>>>(bm, ksc, rtab, qkvrb, kbuf, vbuf, gbuf);
  vtrans_k<<<dim3(32, 4), 256, 0, stream>>>(vbuf, vtb);
  attn_k<<<dim3(16, 16), 512, 0, stream>>>(qkvrb, kbuf, vtb, gbuf, aob);
  gemm_bf16_k<64, false><<<dim3(8, 32), 512, 0, stream>>>(aob, WoT, out, 2048,
                                                          1024, 1024);
}

// Round 7
// 111.816 us; speedup vs baseline: 5.9019x; 1.0412x over previous
//
#include <hip/hip_runtime.h>
#include <hip/hip_bf16.h>
#include <math.h>

typedef unsigned short u16;
typedef unsigned int u32;
typedef __attribute__((ext_vector_type(8))) __bf16 bf16x8;
typedef __attribute__((ext_vector_type(4))) float f32x4;

__device__ inline u16 f2bf(float f) {
  u32 b = __float_as_uint(f);
  b += 0x7FFFu + ((b >> 16) & 1u);
  return (u16)(b >> 16);
}
__device__ inline float bf2f(u16 b) { return __uint_as_float((u32)b << 16); }

// ---------------- f32 -> bf16 elementwise convert -------------------------
__global__ __launch_bounds__(256) void cvt_bf16_k(
    const float* __restrict__ in, u16* __restrict__ out) {
  int i = (blockIdx.x * 256 + threadIdx.x) * 8;
  float4 v0 = *(const float4*)&in[i];
  float4 v1 = *(const float4*)&in[i + 4];
  uint4 pk;
  pk.x = (u32)f2bf(v0.x) | ((u32)f2bf(v0.y) << 16);
  pk.y = (u32)f2bf(v0.z) | ((u32)f2bf(v0.w) << 16);
  pk.z = (u32)f2bf(v1.x) | ((u32)f2bf(v1.y) << 16);
  pk.w = (u32)f2bf(v1.z) | ((u32)f2bf(v1.w) << 16);
  *(uint4*)&out[i] = pk;
}

// ------------- weight prep: grid (32, 92), block (32,8) --------------------
__global__ __launch_bounds__(256) void prep_w_k(
    const float* __restrict__ Wq, const float* __restrict__ Wk,
    const float* __restrict__ Wv, const float* __restrict__ Wvr,
    const float* __restrict__ Wo, const float* __restrict__ Wg,
    const float* __restrict__ Wm, u16* __restrict__ WallT,
    u16* __restrict__ WoT) {
  __shared__ float tile[32][33];
  int k0 = blockIdx.x * 32;
  int ybl = blockIdx.y;
  int tx = threadIdx.x, ty = threadIdx.y;
  const float* src;
  int scol, sN, drow;
  u16* dst;
  if (ybl >= 60) {
    src = Wo; scol = (ybl - 60) * 32; sN = 1024; dst = WoT; drow = scol;
  } else {
    int n0 = ybl * 32;
    if (n0 >= 1792) {  // Wg/Wm/zero region, direct (no LDS)
#pragma unroll
      for (int j = 0; j < 4; ++j) {
        int n = n0 + ty * 4 + j, j2 = n - 1792, k = k0 + tx;
        float val = (j2 < 16) ? Wg[(size_t)k * 16 + j2]
                  : (j2 < 20) ? Wm[(size_t)k * 4 + (j2 - 16)] : 0.f;
        WallT[(size_t)n * 1024 + k] = f2bf(val);
      }
      return;
    }
    dst = WallT; drow = n0;
    if (n0 < 1024) { src = Wq; scol = n0; sN = 1024; }
    else if (n0 < 1280) { src = Wk; scol = n0 - 1024; sN = 256; }
    else if (n0 < 1536) { src = Wv; scol = n0 - 1280; sN = 256; }
    else { src = Wvr; scol = n0 - 1536; sN = 256; }
  }
#pragma unroll
  for (int j = 0; j < 4; ++j)
    tile[ty * 4 + j][tx] = src[(size_t)(k0 + ty * 4 + j) * sN + scol + tx];
  __syncthreads();
#pragma unroll
  for (int j = 0; j < 4; ++j)
    dst[(size_t)(drow + ty * 4 + j) * 1024 + k0 + tx] = f2bf(tile[tx][ty * 4 + j]);
}

// ------------- RoPE table: tab[s][0:32]=cos, [32:64]=sin --------------------
__global__ __launch_bounds__(256) void rope_tab_k(
    const int* __restrict__ positions, float* __restrict__ tab) {
  int idx = blockIdx.x * 256 + threadIdx.x;  // 65536
  int s = idx >> 5, f = idx & 31;
  float inv = __expf(-(float)f * (9.210340371976184f / 32.f));
  float ang = (float)positions[s] * inv;
  tab[(size_t)s * 64 + f] = cosf(ang);
  tab[(size_t)s * 64 + 32 + f] = sinf(ang);
}

// ---------------- bf16 MFMA GEMM: C[M,N] = A[M,K] @ Bt[N,K]^T ---------------
template <int BM, bool BF16_OUT>
__global__ __launch_bounds__(512) void gemm_bf16_k(
    const u16* __restrict__ A, const u16* __restrict__ Bt, void* __restrict__ Cv,
    int M, int N, int K) {
  constexpr int MI = BM / 32;
  __shared__ __align__(16) u16 As[BM * 64];
  __shared__ __align__(16) u16 Bs[128 * 64];
  int tid = threadIdx.x;
  int w = tid >> 6, l = tid & 63;
  int wr = w >> 2, wc = w & 3;
  int lr = l & 15, lg = l >> 4;
  int m0 = blockIdx.y * BM, n0 = blockIdx.x * 128;
  f32x4 zero = {0.f, 0.f, 0.f, 0.f};
  f32x4 acc[MI][2];
#pragma unroll
  for (int mi = 0; mi < MI; ++mi)
#pragma unroll
    for (int ni = 0; ni < 2; ++ni) acc[mi][ni] = zero;

  for (int kt = 0; kt < K; kt += 64) {
    __syncthreads();
#pragma unroll
    for (int c = 0; c < BM * 64 / (8 * 512); ++c) {
      int idx = c * 512 + tid;
      int row = idx >> 3, k0 = (idx & 7) * 8;
      *(uint4*)&As[row * 64 + k0] =
          *(const uint4*)&A[(size_t)(m0 + row) * K + kt + k0];
    }
#pragma unroll
    for (int c = 0; c < 2; ++c) {
      int idx = c * 512 + tid;
      int row = idx >> 3, k0 = (idx & 7) * 8;
      *(uint4*)&Bs[row * 64 + k0] =
          *(const uint4*)&Bt[(size_t)(n0 + row) * K + kt + k0];
    }
    __syncthreads();
#pragma unroll
    for (int kw = 0; kw < 2; ++kw) {
      bf16x8 af[MI], bfr[2];
#pragma unroll
      for (int mi = 0; mi < MI; ++mi)
        af[mi] = *(const bf16x8*)&As[(wr * (BM / 2) + mi * 16 + lr) * 64 + kw * 32 + lg * 8];
#pragma unroll
      for (int ni = 0; ni < 2; ++ni)
        bfr[ni] = *(const bf16x8*)&Bs[(wc * 32 + ni * 16 + lr) * 64 + kw * 32 + lg * 8];
#pragma unroll
      for (int mi = 0; mi < MI; ++mi)
#pragma unroll
        for (int ni = 0; ni < 2; ++ni)
          acc[mi][ni] = __builtin_amdgcn_mfma_f32_16x16x32_bf16(
              af[mi], bfr[ni], acc[mi][ni], 0, 0, 0);
    }
  }
#pragma unroll
  for (int mi = 0; mi < MI; ++mi)
#pragma unroll
    for (int ni = 0; ni < 2; ++ni)
#pragma unroll
      for (int r = 0; r < 4; ++r) {
        int row = m0 + wr * (BM / 2) + mi * 16 + lg * 4 + r;
        int col = n0 + wc * 32 + ni * 16 + lr;
        if (BF16_OUT)
          ((u16*)Cv)[(size_t)row * N + col] = f2bf(acc[mi][ni][r]);
        else
          ((float*)Cv)[(size_t)row * N + col] = acc[mi][ni][r];
      }
}

// ---------------- postprocess (no LDS, no barriers) -------------------------
__global__ __launch_bounds__(256) void postproc_k(
    const float* __restrict__ bm, const float* __restrict__ ksc,
    const float* __restrict__ rtab, u16* __restrict__ qkvrb,
    u16* __restrict__ kb, u16* __restrict__ vb, float* __restrict__ g_out) {
  int s = blockIdx.x, tid = threadIdx.x;
  int lane = tid & 63, w = tid >> 6;
  u16* row = qkvrb + (size_t)s * 1920;
  const float* tr = rtab + (size_t)s * 64;
  if (tid < 16)
    g_out[s * 16 + tid] = 1.f / (1.f + __expf(-bf2f(row[1792 + tid])));
  int h = w, d = lane;
  float c = tr[d >> 1], sn = tr[32 + (d >> 1)];
  {  // v mix -> vb [h][s][d]
    float mixv = 1.f / (1.f + __expf(-(bf2f(row[1808 + h]) + bm[h])));
    float vv = bf2f(row[1280 + h * 64 + d]);
    float rv = bf2f(row[1536 + h * 64 + d]);
    vb[((size_t)h * 2048 + s) * 64 + d] = f2bf(vv + mixv * (rv - vv));
  }
  {  // k: RMSNorm * k_scale + RoPE -> kb [h][s][d]
    float kv = bf2f(row[1024 + h * 64 + d]);
    float ss = kv * kv;
#pragma unroll
    for (int off = 32; off > 0; off >>= 1) ss += __shfl_xor(ss, off);
    float rms = sqrtf(ss * (1.f / 64.f) + 1e-8f);
    float kn = kv / rms * ksc[h * 64 + d];
    float partner = __shfl_xor(kn, 1);
    kb[((size_t)h * 2048 + s) * 64 + d] =
        f2bf((d & 1) ? fmaf(kn, c, partner * sn) : fmaf(kn, c, -partner * sn));
  }
#pragma unroll
  for (int r = 0; r < 4; ++r) {  // q RoPE in-place, pre-scaled by 0.125
    int e = r * 256 + tid;
    int dq = e & 63;
    float cq = tr[dq >> 1], sq = tr[32 + (dq >> 1)];
    float qv = bf2f(row[e]);
    float partner = __shfl_xor(qv, 1);
    float qr = (e & 1) ? fmaf(qv, cq, partner * sq) : fmaf(qv, cq, -partner * sq);
    row[e] = f2bf(qr * 0.125f);
  }
}

// ---------------- vb [h][s][d] -> vtb [h][d][s] -----------------------------
#define TPAD 66
__global__ __launch_bounds__(256) void vtrans_k(const u16* __restrict__ vb,
                                               u16* __restrict__ vtb) {
  __shared__ u16 tile[64 * TPAD];
  int h = blockIdx.y, s0 = blockIdx.x * 64;
  int t = threadIdx.x;
  {
    int r = t >> 2, cb = (t & 3) * 16;
    const u16* src = vb + ((size_t)h * 2048 + s0 + r) * 64 + cb;
    *(uint4*)&tile[r * TPAD + cb] = *(const uint4*)src;
    *(uint4*)&tile[r * TPAD + cb + 8] = *(const uint4*)(src + 8);
  }
  __syncthreads();
  int d = t >> 2, sb = (t & 3) * 16;
  u16 vals[16];
#pragma unroll
  for (int j = 0; j < 16; ++j) vals[j] = tile[(sb + j) * TPAD + d];
  uint4 a, b;
  a.x = (u32)vals[0] | ((u32)vals[1] << 16);
  a.y = (u32)vals[2] | ((u32)vals[3] << 16);
  a.z = (u32)vals[4] | ((u32)vals[5] << 16);
  a.w = (u32)vals[6] | ((u32)vals[7] << 16);
  b.x = (u32)vals[8] | ((u32)vals[9] << 16);
  b.y = (u32)vals[10] | ((u32)vals[11] << 16);
  b.z = (u32)vals[12] | ((u32)vals[13] << 16);
  b.w = (u32)vals[14] | ((u32)vals[15] << 16);
  u16* dst = vtb + ((size_t)h * 64 + d) * 2048 + s0 + sb;
  *(uint4*)dst = a;
  *(uint4*)(dst + 8) = b;
}

// ---------------- MFMA causal attention, swapped-QK, shuffle-P --------------
// grid (16 heads, 32): rb = 31-by (heavy first). 256 threads = 4 waves,
// wave wi owns q-rows wi*16+lr. Lane holds one q-row's scores -> scalar l.
// P[q][key]: lane(lr,lg) holds q=lr, keys {ni*16+lg*4+r}. PV A-frag needs
// lane(lr,lg) to hold q=lr, keys {f*32+lg*8+j} -> block ni=f*2+(lg>>1) from
// lanes src_a=lr+(lg&1)*32, src_b=src_a+16; select ni at the DESTINATION.
#define KPAD 72
__global__ __launch_bounds__(256) void attn_k(
    const u16* __restrict__ qkvrb, const u16* __restrict__ kb,
    const u16* __restrict__ vtb, const float* __restrict__ g,
    u16* __restrict__ aob) {
  __shared__ __align__(16) u16 Ks[64 * KPAD];
  __shared__ __align__(16) u16 Vt[64 * KPAD];
  int head = blockIdx.x, hkv = head >> 2;
  int rb = 31 - (int)blockIdx.y;
  int row0 = rb * 64;
  int tid = threadIdx.x;
  int wi = tid >> 6, l = tid & 63;
  int lr = l & 15, lg = l >> 4;
  int skey = tid >> 2, sdb = (tid & 3) * 16;
  f32x4 zero = {0.f, 0.f, 0.f, 0.f};
  // q fragment (B-frag: col=q=lr, k=lg*8), pre-scaled by 0.125 in postproc
  const u16* qrow = qkvrb + (size_t)(row0 + wi * 16 + lr) * 1920 + head * 64;
  bf16x8 qf0 = *(const bf16x8*)&qrow[lg * 8];
  bf16x8 qf1 = *(const bf16x8*)&qrow[32 + lg * 8];
  f32x4 acc_o[4];
#pragma unroll
  for (int nd = 0; nd < 4; ++nd) acc_o[nd] = zero;
  float l_part = 0.f;
  int qglob = row0 + wi * 16 + lr;
  int src_a = lr + (lg & 1) * 32, src_b = src_a + 16;
  // prefetch chunk 0
  uint4 rk0, rk1, rv0, rv1;
  {
    const u16* kp = kb + ((size_t)hkv * 2048 + skey) * 64 + sdb;
    rk0 = *(const uint4*)kp;
    rk1 = *(const uint4*)(kp + 8);
    const u16* vp = vtb + ((size_t)(hkv * 64 + skey)) * 2048 + sdb;
    rv0 = *(const uint4*)vp;
    rv1 = *(const uint4*)(vp + 8);
  }
#pragma unroll 1
  for (int c = 0; c <= rb; ++c) {
    *(uint4*)&Ks[skey * KPAD + sdb] = rk0;
    *(uint4*)&Ks[skey * KPAD + sdb + 8] = rk1;
    *(uint4*)&Vt[skey * KPAD + sdb] = rv0;
    *(uint4*)&Vt[skey * KPAD + sdb + 8] = rv1;
    __syncthreads();
    if (c < rb) {  // prefetch next chunk during compute
      int nb = (c + 1) * 64;
      const u16* kp = kb + ((size_t)hkv * 2048 + nb + skey) * 64 + sdb;
      rk0 = *(const uint4*)kp;
      rk1 = *(const uint4*)(kp + 8);
      const u16* vp = vtb + ((size_t)(hkv * 64 + skey)) * 2048 + nb + sdb;
      rv0 = *(const uint4*)vp;
      rv1 = *(const uint4*)(vp + 8);
    }
    int kbase = c * 64;
    // swapped QK^T: A=K (row=key), B=q (col=q) -> D[key][q]
    f32x4 sa[4];
#pragma unroll
    for (int ni = 0; ni < 4; ++ni) {
      bf16x8 a0 = *(const bf16x8*)&Ks[(ni * 16 + lr) * KPAD + lg * 8];
      bf16x8 a1 = *(const bf16x8*)&Ks[(ni * 16 + lr) * KPAD + 32 + lg * 8];
      f32x4 t = __builtin_amdgcn_mfma_f32_16x16x32_bf16(a0, qf0, zero, 0, 0, 0);
      sa[ni] = __builtin_amdgcn_mfma_f32_16x16x32_bf16(a1, qf1, t, 0, 0, 0);
    }
    bool diag = (c == rb);
    // softclamp softmax: p = exp(50*tanh(s/50)-50), row-sum into scalar
    u32 pkw[4][2];
#pragma unroll
    for (int ni = 0; ni < 4; ++ni) {
      float pv[4];
#pragma unroll
      for (int r = 0; r < 4; ++r) {
        float sv = sa[ni][r];
        float e = __expf(sv * 0.04f);
        float p = __expf(-100.f * __builtin_amdgcn_rcpf(e + 1.f));
        if (diag && (kbase + ni * 16 + lg * 4 + r) > qglob) p = 0.f;
        pv[r] = p;
        l_part += p;
      }
      asm("v_cvt_pk_bf16_f32 %0, %1, %2" : "=v"(pkw[ni][0]) : "v"(pv[0]), "v"(pv[1]));
      asm("v_cvt_pk_bf16_f32 %0, %1, %2" : "=v"(pkw[ni][1]) : "v"(pv[2]), "v"(pv[3]));
    }
    // gather ALL four ni-blocks, then select at destination (ni = f*2+(lg>>1))
    union { u32 w[4]; bf16x8 v; } pf0, pf1;
    {
      u32 t0[4], t1[4], t2[4], t3[4];
#define GATHER(T, NI)                          \
      T[0] = __shfl((int)pkw[NI][0], src_a);   \
      T[1] = __shfl((int)pkw[NI][1], src_a);   \
      T[2] = __shfl((int)pkw[NI][0], src_b);   \
      T[3] = __shfl((int)pkw[NI][1], src_b);
      GATHER(t0, 0)
      GATHER(t1, 1)
      GATHER(t2, 2)
      GATHER(t3, 3)
#undef GATHER
      bool hi = (lg & 2) != 0;
#pragma unroll
      for (int kq = 0; kq < 4; ++kq) {
        pf0.w[kq] = hi ? t1[kq] : t0[kq];
        pf1.w[kq] = hi ? t3[kq] : t2[kq];
      }
    }
    // PV: A=P (row=q, k=key), B=V^T (col=d, k=key)
#pragma unroll
    for (int nd = 0; nd < 4; ++nd) {
      bf16x8 v0 = *(const bf16x8*)&Vt[(nd * 16 + lr) * KPAD + lg * 8];
      bf16x8 v1 = *(const bf16x8*)&Vt[(nd * 16 + lr) * KPAD + 32 + lg * 8];
      acc_o[nd] = __builtin_amdgcn_mfma_f32_16x16x32_bf16(pf0.v, v0, acc_o[nd], 0, 0, 0);
      acc_o[nd] = __builtin_amdgcn_mfma_f32_16x16x32_bf16(pf1.v, v1, acc_o[nd], 0, 0, 0);
    }
    __syncthreads();
  }
  // epilogue: l[q=lr] = sum over lg; redistribute to output rows lg*4+r
  l_part += __shfl_xor(l_part, 16);
  l_part += __shfl_xor(l_part, 32);
#pragma unroll
  for (int r = 0; r < 4; ++r) {
    int row = row0 + wi * 16 + lg * 4 + r;
    float lv = __shfl(l_part, lg * 4 + r);
    float sc = g[row * 16 + head] * __builtin_amdgcn_rcpf(lv);
#pragma unroll
    for (int nd = 0; nd < 4; ++nd)
      aob[(size_t)row * 1024 + head * 64 + nd * 16 + lr] =
          f2bf(acc_o[nd][r] * sc);
  }
}

extern "C" void kernel_launch(void* const* d_in, const int* in_sizes, int n_in,
                              void* d_out, int out_size, void* d_ws,
                              size_t ws_size, hipStream_t stream) {
  const float* x = (const float*)d_in[0];
  const int* positions = (const int*)d_in[1];
  const float* Wq = (const float*)d_in[3];
  const float* Wk = (const float*)d_in[4];
  const float* Wv = (const float*)d_in[5];
  const float* Wo = (const float*)d_in[6];
  const float* Wg = (const float*)d_in[7];
  const float* Wm = (const float*)d_in[8];
  const float* bm = (const float*)d_in[9];
  const float* Wvr = (const float*)d_in[10];
  const float* ksc = (const float*)d_in[11];
  float* out = (float*)d_out;

  u16* xb = (u16*)d_ws;                            // 2048*1024
  u16* WallT = xb + (size_t)2048 * 1024;           // 1920*1024
  u16* WoT = WallT + (size_t)1920 * 1024;          // 1024*1024
  u16* qkvrb = WoT + (size_t)1024 * 1024;          // 2048*1920
  u16* kbuf = qkvrb + (size_t)2048 * 1920;         // 4*2048*64
  u16* vbuf = kbuf + (size_t)4 * 2048 * 64;
  u16* vtb = vbuf + (size_t)4 * 2048 * 64;
  float* gbuf = (float*)(vtb + (size_t)4 * 2048 * 64);  // 2048*16 f32
  float* rtab = gbuf + (size_t)2048 * 16;               // 2048*64 f32
  u16* aob = xb;  // xb dead after gemm1

  cvt_bf16_k<<<1024, 256, 0, stream>>>(x, xb);
  prep_w_k<<<dim3(32, 92), dim3(32, 8), 0, stream>>>(Wq, Wk, Wv, Wvr, Wo, Wg,
                                                     Wm, WallT, WoT);
  rope_tab_k<<<256, 256, 0, stream>>>(positions, rtab);
  gemm_bf16_k<128, true><<<dim3(15, 16), 512, 0, stream>>>(xb, WallT, qkvrb,
                                                           2048, 1920, 1024);
  postproc_k<<<2048, 256, 0, stream>>>(bm, ksc, rtab, qkvrb, kbuf, vbuf, gbuf);
  vtrans_k<<<dim3(32, 4), 256, 0, stream>>>(vbuf, vtb);
  attn_k<<<dim3(16, 32), 256, 0, stream>>>(qkvrb, kbuf, vtb, gbuf, aob);
  gemm_bf16_k<64, false><<<dim3(8, 32), 512, 0, stream>>>(aob, WoT, out, 2048,
                                                          1024, 1024);
}